// Round 12
// baseline (202.825 us; speedup 1.0000x reference)
//
#include <hip/hip_runtime.h>
#include <hip/hip_bf16.h>

#define N_INS 16384
#define N_ATT 8192
#define KDIM  64

typedef __attribute__((ext_vector_type(8))) short bf16x8;
typedef __attribute__((ext_vector_type(4))) float f32x4;

// ws layout (bytes):
// 0:       bf16 Ucb[8192*64] (1 MiB, fragment-order tiles)   [K1 writes all]
// 1048576: float cpr[64][64]                                  [K1 writes all]
// 1064960: float cpc[32][64]                                  [K1 writes all]
// 1073152: float Aseg[4096]   (atomic-accumulated, K1 zeroes)
// 1089536: float Bseg[4096]   (atomic-accumulated, K1 zeroes)
// 1105920: double Gacc[96]    ([0,64)=G shards, [64,80)=Uu, [80,96)=Vv; K1 zeroes)
// 1106688: unsigned tickets[17] (16 shards + 1 global; K1 zeroes)
#define OFF_UCB    0
#define OFF_CPR    1048576
#define OFF_CPC    1064960
#define OFF_ASEG   1073152
#define OFF_BSEG   1089536
#define OFF_GACC   1105920
#define OFF_TK     1106688

#define NBLK_PASS  48             // [0,32): Ur 512-row blocks; [32,48): Uc
#define NBLK_HEAVY 2048
#define NBLK_K2    (NBLK_PASS + NBLK_HEAVY)   // 2096 = 16 * 131

__device__ __forceinline__ unsigned short f2bf(float x) {
    unsigned u = __float_as_uint(x);
    u = (u + 0x7FFFu + ((u >> 16) & 1u)) >> 16;   // RNE
    return (unsigned short)u;
}

__device__ __forceinline__ float wave_red(float v) {
#pragma unroll
    for (int o = 32; o > 0; o >>= 1) v += __shfl_down(v, o, 64);
    return v;
}

// ---- K1: convert Uc->bf16 fragment tiles (store-coalesced), colsums, zero accs ----
// Ucb tile t (2KB, rows 16t..16t+15): output chunk o (0..127) at t*2048+o*16.
// Inverse map: o<64 -> q=o>>4, m=o&15 ; o>=64 -> q=4+((o-64)>>4), m=(o-64)&15.
// Consecutive threads write consecutive 16B (coalesced); reads are small gathers.
// blocks [0,128): convert. [128,192): Ur colsums (256 rows) -> cpr[64].
// [192,224): Uc colsums -> cpc[32]. block 224: zero Aseg/Bseg/Gacc/tickets.
__global__ void k_prep(const float* __restrict__ Ur, const float* __restrict__ Uc,
                       float* __restrict__ cpr, float* __restrict__ cpc,
                       unsigned short* __restrict__ Ucb,
                       float* __restrict__ Aseg, float* __restrict__ Bseg,
                       double* __restrict__ Gacc, unsigned* __restrict__ tickets) {
    int blk = blockIdx.x, tid = threadIdx.x;
    if (blk < 128) {
        int gid = blk * 256 + tid;
        for (int c = gid; c < N_ATT * 8; c += 32768) {   // 65536 chunks, 2/thread
            int t = c >> 7, o = c & 127;
            int q, m;
            if (o < 64) { q = o >> 4; m = o & 15; }
            else        { q = 4 + ((o - 64) >> 4); m = (o - 64) & 15; }
            int r = t * 16 + m;
            const float4* src = (const float4*)(Uc + (size_t)r * 64 + q * 8);
            float4 x0 = src[0], x1 = src[1];
            uint4 v;
            v.x = (unsigned)f2bf(x0.x) | ((unsigned)f2bf(x0.y) << 16);
            v.y = (unsigned)f2bf(x0.z) | ((unsigned)f2bf(x0.w) << 16);
            v.z = (unsigned)f2bf(x1.x) | ((unsigned)f2bf(x1.y) << 16);
            v.w = (unsigned)f2bf(x1.z) | ((unsigned)f2bf(x1.w) << 16);
            *(uint4*)((unsigned char*)Ucb + (size_t)c * 16) = v;
        }
        return;
    }
    if (blk == 224) {
        float4 z4 = {0.f, 0.f, 0.f, 0.f};
        for (int i = tid; i < 1024; i += 256) ((float4*)Aseg)[i] = z4;
        for (int i = tid; i < 1024; i += 256) ((float4*)Bseg)[i] = z4;
        if (tid < 96) Gacc[tid] = 0.0;
        if (tid < 17) tickets[tid] = 0u;
        return;
    }
    __shared__ float cs2[256];
    bool isUr = blk < 192;
    int b = isUr ? (blk - 128) : (blk - 192);
    const float* base = (isUr ? Ur : Uc) + (size_t)b * 256 * KDIM;
    float* dst = (isUr ? cpr : cpc) + b * 64;
    int col = tid & 63, r0 = tid >> 6;
    float s = 0.f;
    for (int r = r0; r < 256; r += 4) s += base[r * KDIM + col];
    cs2[tid] = s;
    __syncthreads();
    if (tid < 64) dst[tid] = cs2[tid] + cs2[tid + 64] + cs2[tid + 128] + cs2[tid + 192];
}

// ---- K2: pass (48 blocks, first) + heavy (2048) + sharded-ticket final ----
// R11 lesson: 1.57M fire-and-forget global atomics into 32KB WERE the kernel
// (WRITE_SIZE 6.3MB at 52 GB/s == dur). Now pass accumulates in LDS Part and
// contributes 4096 coalesced global atomics per block (48x4096=196K ops, 8x
// less traffic). Ticket is 2-level sharded (16x131 + 16->1) to avoid the
// single-address serialization chain (R3: ~17ns per same-address atomic).
__global__ __launch_bounds__(256)
void k_main(const float* __restrict__ Ur, const float* __restrict__ Uc,
            const unsigned char* __restrict__ Ucb,
            const float* __restrict__ cpr, const float* __restrict__ cpc,
            float* __restrict__ Aseg, float* __restrict__ Bseg,
            double* __restrict__ Gacc, unsigned* __restrict__ tickets,
            float* __restrict__ out) {
    __shared__ __align__(16) unsigned char smem[18816];
    __shared__ float gshW[4];
    __shared__ int flagS;
    int tid = threadIdx.x, blk = blockIdx.x;
    int wvi = tid >> 6, lane = tid & 63;

    if (blk < NBLK_PASS) {
        // ---------- pass: 512 rows, LDS Part accumulation, block-level atomic fold ----
        float* Part = (float*)smem;                  // 4096 f32 = 16384 B
        int*   bins = (int*)(smem + 16384);          // 512 ints = 2048 B
        float* wv   = (float*)(smem + 18432);        // 64 f32
        float* psum = (float*)(smem + 18688);        // 4 f32
        bool isUr = blk < 32;
        int b = isUr ? blk : (blk - 32);
        const float* M = isUr ? Ur : Uc;
        float* Seg = isUr ? Aseg : Bseg;
        int base_row = b * 512;

        if (tid < 64) {                              // weights = colsum of OTHER matrix
            const float* cpw = isUr ? cpc : cpr;
            int nbw = isUr ? 32 : 64;
            float s = 0.f;
            for (int p = 0; p < nbw; ++p) s += cpw[p * 64 + tid];
            wv[tid] = s;
        }
        for (int i = tid; i < 4096; i += 256) Part[i] = 0.f;
        __syncthreads();

        // phase 1: 2 rows per thread, pure-VALU argmax + dot
        float uu = 0.f;
#pragma unroll
        for (int h = 0; h < 2; ++h) {
            int row = base_row + h * 256 + tid;
            const float* rp = M + (size_t)row * KDIM;
            float best = -1e30f; int bidx = 0; float u = 0.f;
#pragma unroll
            for (int k = 0; k < 64; k += 4) {
                float4 v = *(const float4*)(rp + k);
                if (v.x > best) { best = v.x; bidx = k; }
                if (v.y > best) { best = v.y; bidx = k + 1; }
                if (v.z > best) { best = v.z; bidx = k + 2; }
                if (v.w > best) { best = v.w; bidx = k + 3; }
                u += v.x * wv[k] + v.y * wv[k + 1] + v.z * wv[k + 2] + v.w * wv[k + 3];
            }
            bins[h * 256 + tid] = bidx;
            uu += u * __log2f(u);
        }
        {
            float pw = wave_red(uu);
            if (lane == 0) psum[wvi] = pw;
        }
        __syncthreads();
        // phase 2: wave handles 128 rows; coalesced row re-read + 1 ds_add per row
        {
            int r0 = wvi * 128;
            const float* Mb = M + (size_t)(base_row + r0) * 64 + lane;
#pragma unroll 4
            for (int r = 0; r < 128; ++r) {
                int bb = bins[r0 + r];               // LDS broadcast: free
                float val = Mb[(size_t)r * 64];      // coalesced 256B
                atomicAdd(&Part[bb * 64 + lane], val);  // 2/bank: free
            }
        }
        __syncthreads();
        // block fold: 4096 coalesced global atomics (16/thread)
        for (int i = tid; i < 4096; i += 256)
            atomicAdd(&Seg[i], Part[i]);
        if (tid == 0) {
            double* acc = Gacc + (isUr ? (64 + (b & 15)) : (80 + b));
            atomicAdd(acc, (double)(psum[0] + psum[1] + psum[2] + psum[3]));
        }
    } else {
        // ---------- heavy: G += d*log2(d), bf16 MFMA, register-pipelined B ----------
        int hb = blk - NBLK_PASS;
        int quad = lane >> 4, m = lane & 15;
        int rb = hb & 127, cc = hb >> 7;
        int row0 = rb * 128 + wvi * 32;
        bf16x8 a[2][2];
#pragma unroll
        for (int t = 0; t < 2; ++t) {
            int ridx = row0 + t * 16 + m;
            const float* rp = Ur + (size_t)ridx * 64 + quad * 8;
#pragma unroll
            for (int h = 0; h < 2; ++h) {
                const float* rph = rp + h * 32;
                float4 x0 = *(const float4*)rph;
                float4 x1 = *(const float4*)(rph + 4);
                bf16x8 f;
                f[0] = (short)f2bf(x0.x); f[1] = (short)f2bf(x0.y);
                f[2] = (short)f2bf(x0.z); f[3] = (short)f2bf(x0.w);
                f[4] = (short)f2bf(x1.x); f[5] = (short)f2bf(x1.y);
                f[6] = (short)f2bf(x1.z); f[7] = (short)f2bf(x1.w);
                a[t][h] = f;
            }
        }
        const unsigned char* gB = Ucb + (size_t)(cc * 32) * 2048 + lane * 16;
        bf16x8 c00 = *(const bf16x8*)(gB);
        bf16x8 c01 = *(const bf16x8*)(gB + 1024);
        bf16x8 c10 = *(const bf16x8*)(gB + 2048);
        bf16x8 c11 = *(const bf16x8*)(gB + 3072);
        float g = 0.f;
#pragma unroll 1
        for (int pt = 0; pt < 16; ++pt) {
            int npt = (pt < 15) ? (pt + 1) : 15;
            const unsigned char* nb = gB + (size_t)npt * 4096;
            bf16x8 n00 = *(const bf16x8*)(nb);
            bf16x8 n01 = *(const bf16x8*)(nb + 1024);
            bf16x8 n10 = *(const bf16x8*)(nb + 2048);
            bf16x8 n11 = *(const bf16x8*)(nb + 3072);
            f32x4 acc00 = {0.f,0.f,0.f,0.f}, acc01 = {0.f,0.f,0.f,0.f};
            f32x4 acc10 = {0.f,0.f,0.f,0.f}, acc11 = {0.f,0.f,0.f,0.f};
            acc00 = __builtin_amdgcn_mfma_f32_16x16x32_bf16(a[0][0], c00, acc00, 0, 0, 0);
            acc00 = __builtin_amdgcn_mfma_f32_16x16x32_bf16(a[0][1], c01, acc00, 0, 0, 0);
            acc10 = __builtin_amdgcn_mfma_f32_16x16x32_bf16(a[1][0], c00, acc10, 0, 0, 0);
            acc10 = __builtin_amdgcn_mfma_f32_16x16x32_bf16(a[1][1], c01, acc10, 0, 0, 0);
            acc01 = __builtin_amdgcn_mfma_f32_16x16x32_bf16(a[0][0], c10, acc01, 0, 0, 0);
            acc01 = __builtin_amdgcn_mfma_f32_16x16x32_bf16(a[0][1], c11, acc01, 0, 0, 0);
            acc11 = __builtin_amdgcn_mfma_f32_16x16x32_bf16(a[1][0], c10, acc11, 0, 0, 0);
            acc11 = __builtin_amdgcn_mfma_f32_16x16x32_bf16(a[1][1], c11, acc11, 0, 0, 0);
            // tile-sum is permutation-invariant -> C/D layout irrelevant;
            // dropping +eps*S (~2e-6 vs d~16) perturbs mi_org ~2e-7 << threshold
#pragma unroll
            for (int e = 0; e < 4; ++e) {
                float d0 = acc00[e]; g += d0 * __log2f(d0);
                float d1 = acc01[e]; g += d1 * __log2f(d1);
                float d2 = acc10[e]; g += d2 * __log2f(d2);
                float d3 = acc11[e]; g += d3 * __log2f(d3);
            }
            c00 = n00; c01 = n01; c10 = n10; c11 = n11;
        }
        float gw = wave_red(g);
        if (lane == 0) gshW[wvi] = gw;
        __syncthreads();
        if (tid == 0) {
            float gs = gshW[0] + gshW[1] + gshW[2] + gshW[3];
            atomicAdd(&Gacc[hb & 63], (double)gs);   // 32 blocks/shard
        }
    }

    // ---------- common tail: drain own atomics, 2-level sharded ticket ----------
    __builtin_amdgcn_s_waitcnt(0);
    __syncthreads();
    if (tid == 0) {
        flagS = 0;
        unsigned old = atomicAdd(&tickets[blk & 15], 1u);
        if (old == (NBLK_K2 / 16) - 1) {             // last of this shard's 131
            unsigned old2 = atomicAdd(&tickets[16], 1u);
            flagS = (old2 == 15u);
        }
    }
    __syncthreads();
    if (!flagS) return;

    // final: inputs are atomic-written (coherent) or K1-produced (boundary-coherent)
    float*  Prx = (float*)smem;
    float*  Pry = (float*)(smem + 256);
    double* sc  = (double*)(smem + 512);             // S,G,Uu,Vv
    double* red = (double*)(smem + 1024);            // 256 f64
    if (tid < 64) {
        double sa = 0.0, sb = 0.0;
        for (int p = 0; p < 64; ++p) sa += (double)cpr[p * 64 + tid];
        for (int p = 0; p < 32; ++p) sb += (double)cpc[p * 64 + tid];
        red[tid] = sa * sb;
        Prx[tid] = 0.f; Pry[tid] = 0.f;
    }
    __syncthreads();
    if (tid == 0) {
        double s = 0.0;
        for (int k = 0; k < 64; ++k) s += red[k];
        sc[0] = s;
        double gg = 0.0;
        for (int k = 0; k < 64; ++k) gg += Gacc[k];
        sc[1] = gg;
    } else if (tid == 1) {
        double s = 0.0;
        for (int k = 64; k < 80; ++k) s += Gacc[k];
        sc[2] = s;
    } else if (tid == 2) {
        double s = 0.0;
        for (int k = 80; k < 96; ++k) s += Gacc[k];
        sc[3] = s;
    }
    __syncthreads();
    double S = sc[0];
    int p = tid >> 2, q0 = (tid & 3) * 16;
    float tloc[16];
    {
        float prow_sum = 0.f;
        for (int qi = 0; qi < 16; ++qi) {
            int q = q0 + qi;
            double s = 0.0;
            for (int k = 0; k < 64; ++k)
                s += (double)Aseg[p * 64 + k] * (double)Bseg[q * 64 + k];
            float t = (float)(s / S);
            tloc[qi] = t;
            prow_sum += t;
            atomicAdd(&Pry[q], t);
        }
        atomicAdd(&Prx[p], prow_sum);
    }
    __syncthreads();
    {
        const double EPSd = 1e-15;
        double part = 0.0;
        for (int qi = 0; qi < 16; ++qi) {
            double t = (double)tloc[qi];
            double txy = (double)Prx[p] * (double)Pry[q0 + qi];
            part += t * log((t + EPSd) / (txy + EPSd));
        }
        red[tid] = part;
    }
    __syncthreads();
    for (int s2 = 128; s2 > 0; s2 >>= 1) {
        if (tid < s2) red[tid] += red[tid + s2];
        __syncthreads();
    }
    if (tid == 0) {
        const double inv_ln2 = 1.4426950408889634;
        double mi_red = red[0] * inv_ln2;
        double G = sc[1], Uu = sc[2], Vv = sc[3];
        double log2S = log(S) * inv_ln2;
        double mi_org = G / S + log2S - (Uu + Vv) / S;
        double loss = log(1.0 + fabs(1.0 - mi_red / mi_org));
        out[0] = (float)loss;
    }
}

extern "C" void kernel_launch(void* const* d_in, const int* in_sizes, int n_in,
                              void* d_out, int out_size, void* d_ws, size_t ws_size,
                              hipStream_t stream) {
    const float* Ur = (const float*)d_in[0];
    const float* Uc = (const float*)d_in[1];
    float* out = (float*)d_out;
    char* ws = (char*)d_ws;
    unsigned short* Ucb = (unsigned short*)(ws + OFF_UCB);
    float* cpr   = (float*)(ws + OFF_CPR);
    float* cpc   = (float*)(ws + OFF_CPC);
    float* Aseg  = (float*)(ws + OFF_ASEG);
    float* Bseg  = (float*)(ws + OFF_BSEG);
    double* Gacc = (double*)(ws + OFF_GACC);
    unsigned* tickets = (unsigned*)(ws + OFF_TK);

    k_prep<<<225, 256, 0, stream>>>(Ur, Uc, cpr, cpc, Ucb, Aseg, Bseg, Gacc, tickets);
    k_main<<<NBLK_K2, 256, 0, stream>>>(Ur, Uc, (const unsigned char*)Ucb,
                                        cpr, cpc, Aseg, Bseg, Gacc, tickets, out);
}

// Round 13
// 194.071 us; speedup vs baseline: 1.0451x; 1.0451x over previous
//
#include <hip/hip_runtime.h>
#include <hip/hip_bf16.h>

#define N_INS 16384
#define N_ATT 8192
#define KDIM  64

typedef __attribute__((ext_vector_type(8))) short bf16x8;
typedef __attribute__((ext_vector_type(4))) float f32x4;

// ws layout (bytes):
// 0:       bf16 Ucb[8192*64] (1 MiB, fragment-order tiles)     [K1 writes all]
// 1048576: float cpr[64][64]                                    [K1 writes all]
// 1064960: float cpc[32][64]                                    [K1 writes all]
// 1073152: float Aseg[4096]   (atomic, zeroed by hipMemsetAsync)
// 1089536: float Bseg[4096]   (atomic, zeroed by memset)
// 1105920: double Gacc[96]    ([0,64)=G, [64,80)=Uu, [80,96)=Vv; memset)
// 1106688: unsigned tickets[17] (16 shards + 1 global; memset)
#define OFF_UCB    0
#define OFF_CPR    1048576
#define OFF_CPC    1064960
#define OFF_ASEG   1073152
#define OFF_BSEG   1089536
#define OFF_GACC   1105920
#define OFF_TK     1106688
#define ZERO_BYTES 33604          // Aseg..tickets inclusive

#define NBLK_U     96             // K2 blocks [0,96): u-dot ([0,64)=Ur, [64,96)=Uc)
#define NBLK_HEAVY 2048           // K2 blocks [96, 2144)
#define NBLK_K2    (NBLK_U + NBLK_HEAVY)     // 2144 = 16 * 134

__device__ __forceinline__ unsigned short f2bf(float x) {
    unsigned u = __float_as_uint(x);
    u = (u + 0x7FFFu + ((u >> 16) & 1u)) >> 16;   // RNE
    return (unsigned short)u;
}

__device__ __forceinline__ float wave_red(float v) {
#pragma unroll
    for (int o = 32; o > 0; o >>= 1) v += __shfl_down(v, o, 64);
    return v;
}

// ---- K1: convert + colsums + argmax/segment-sums (the colsum-independent
// half of the old "pass" — it rides along with convert instead of being a
// 57us serialized tail). Aseg/Bseg pre-zeroed by hipMemsetAsync.
// blocks [0,128):   convert Uc->bf16 fragment tiles (store-coalesced)
// blocks [128,192): Ur colsums (256 rows)  -> cpr[b]
// blocks [192,224): Uc colsums (256 rows)  -> cpc[b]
// blocks [224,288): Ur argmax+segsum (256 rows) -> atomic fold into Aseg
// blocks [288,320): Uc argmax+segsum (256 rows) -> atomic fold into Bseg
__global__ __launch_bounds__(256)
void k_prep(const float* __restrict__ Ur, const float* __restrict__ Uc,
            float* __restrict__ cpr, float* __restrict__ cpc,
            unsigned short* __restrict__ Ucb,
            float* __restrict__ Aseg, float* __restrict__ Bseg) {
    __shared__ __align__(16) unsigned char smem[17408];
    int blk = blockIdx.x, tid = threadIdx.x;
    if (blk < 128) {
        // Ucb tile t (2KB, rows 16t..16t+15), chunk o at t*2048+o*16;
        // o<64 -> q=o>>4,m=o&15 ; o>=64 -> q=4+((o-64)>>4), m=(o-64)&15.
        int gid = blk * 256 + tid;
        for (int c = gid; c < N_ATT * 8; c += 32768) {
            int t = c >> 7, o = c & 127;
            int q, m;
            if (o < 64) { q = o >> 4; m = o & 15; }
            else        { q = 4 + ((o - 64) >> 4); m = (o - 64) & 15; }
            int r = t * 16 + m;
            const float4* src = (const float4*)(Uc + (size_t)r * 64 + q * 8);
            float4 x0 = src[0], x1 = src[1];
            uint4 v;
            v.x = (unsigned)f2bf(x0.x) | ((unsigned)f2bf(x0.y) << 16);
            v.y = (unsigned)f2bf(x0.z) | ((unsigned)f2bf(x0.w) << 16);
            v.z = (unsigned)f2bf(x1.x) | ((unsigned)f2bf(x1.y) << 16);
            v.w = (unsigned)f2bf(x1.z) | ((unsigned)f2bf(x1.w) << 16);
            *(uint4*)((unsigned char*)Ucb + (size_t)c * 16) = v;
        }
        return;
    }
    if (blk < 224) {
        float* cs2 = (float*)smem;
        bool isUr = blk < 192;
        int b = isUr ? (blk - 128) : (blk - 192);
        const float* base = (isUr ? Ur : Uc) + (size_t)b * 256 * KDIM;
        float* dst = (isUr ? cpr : cpc) + b * 64;
        int col = tid & 63, r0 = tid >> 6;
        float s = 0.f;
        for (int r = r0; r < 256; r += 4) s += base[r * KDIM + col];
        cs2[tid] = s;
        __syncthreads();
        if (tid < 64) dst[tid] = cs2[tid] + cs2[tid + 64] + cs2[tid + 128] + cs2[tid + 192];
        return;
    }
    // ---- argmax + segment-sum (R8-proven structure, no colsum dependency) ----
    float* Part = (float*)smem;                      // 4096 f32
    int*   bins = (int*)(smem + 16384);              // 256 ints
    bool isUr = blk < 288;
    int b = isUr ? (blk - 224) : (blk - 288);
    const float* M = isUr ? Ur : Uc;
    float* Seg = isUr ? Aseg : Bseg;
    int base_row = b * 256;
    int wvi = tid >> 6, lane = tid & 63;

    for (int i = tid; i < 4096; i += 256) Part[i] = 0.f;
    __syncthreads();
    {   // phase 1: row-per-thread argmax (pure VALU)
        const float* rp = M + (size_t)(base_row + tid) * KDIM;
        float best = -1e30f; int bidx = 0;
#pragma unroll
        for (int k = 0; k < 64; k += 4) {
            float4 v = *(const float4*)(rp + k);
            if (v.x > best) { best = v.x; bidx = k; }
            if (v.y > best) { best = v.y; bidx = k + 1; }
            if (v.z > best) { best = v.z; bidx = k + 2; }
            if (v.w > best) { best = v.w; bidx = k + 3; }
        }
        bins[tid] = bidx;
    }
    __syncthreads();
    {   // phase 2: one fire-and-forget ds_add per row per wave
        int r0 = wvi * 64;
        const float* Mb = M + (size_t)(base_row + r0) * 64 + lane;
#pragma unroll 4
        for (int r = 0; r < 64; ++r) {
            int bb = bins[r0 + r];                   // LDS broadcast: free
            float val = Mb[(size_t)r * 64];          // coalesced 256B
            atomicAdd(&Part[bb * 64 + lane], val);   // 2/bank: free
        }
    }
    __syncthreads();
    for (int i = tid; i < 4096; i += 256)            // coalesced global fold
        atomicAdd(&Seg[i], Part[i]);
}

// ---- K2: u-dots (96 blocks, overlap heavy) + heavy (2048) + ticketed final ----
// Max LDS across paths ~3KB, target VGPR <=64 (R10/R12 lesson: the fattest
// path's envelope throttles heavy's residency — heavy is the latency-bound
// pig at ~18.5us VALU floor spread over 130us).
__global__ __launch_bounds__(256)
void k_main(const float* __restrict__ Ur, const float* __restrict__ Uc,
            const unsigned char* __restrict__ Ucb,
            const float* __restrict__ cpr, const float* __restrict__ cpc,
            const float* __restrict__ Aseg, const float* __restrict__ Bseg,
            double* __restrict__ Gacc, unsigned* __restrict__ tickets,
            float* __restrict__ out) {
    __shared__ __align__(16) unsigned char smem[3328];
    __shared__ int flagS;
    int tid = threadIdx.x, blk = blockIdx.x;
    int wvi = tid >> 6, lane = tid & 63;

    if (blk < NBLK_U) {
        // ---------- u-dot: u=row.colsum(other), Gacc += u*log2(u) ----------
        float* wv = (float*)smem;
        bool isUr = blk < 64;
        int b = isUr ? blk : (blk - 64);
        const float* M = isUr ? Ur : Uc;
        int base_row = b * 256;
        if (tid < 64) {
            const float* cpw = isUr ? cpc : cpr;
            int nbw = isUr ? 32 : 64;
            float s = 0.f;
            for (int p = 0; p < nbw; ++p) s += cpw[p * 64 + tid];
            wv[tid] = s;
        }
        __syncthreads();
        const float* rp = M + (size_t)(base_row + tid) * KDIM;
        float u = 0.f;
#pragma unroll
        for (int k = 0; k < 64; k += 4) {
            float4 v = *(const float4*)(rp + k);
            u += v.x * wv[k] + v.y * wv[k + 1] + v.z * wv[k + 2] + v.w * wv[k + 3];
        }
        float pw = wave_red(u * __log2f(u));
        if (lane == 0)
            atomicAdd(&Gacc[(isUr ? 64 : 80) + (b & 15)], (double)pw);
    } else {
        // ---------- heavy: G += d*log2(d), bf16 MFMA, register-pipelined B ----------
        float* gshW = (float*)smem;
        int hb = blk - NBLK_U;
        int quad = lane >> 4, m = lane & 15;
        int rb = hb & 127, cc = hb >> 7;
        int row0 = rb * 128 + wvi * 32;
        bf16x8 a[2][2];
#pragma unroll
        for (int t = 0; t < 2; ++t) {
            int ridx = row0 + t * 16 + m;
            const float* rp = Ur + (size_t)ridx * 64 + quad * 8;
#pragma unroll
            for (int h = 0; h < 2; ++h) {
                const float* rph = rp + h * 32;
                float4 x0 = *(const float4*)rph;
                float4 x1 = *(const float4*)(rph + 4);
                bf16x8 f;
                f[0] = (short)f2bf(x0.x); f[1] = (short)f2bf(x0.y);
                f[2] = (short)f2bf(x0.z); f[3] = (short)f2bf(x0.w);
                f[4] = (short)f2bf(x1.x); f[5] = (short)f2bf(x1.y);
                f[6] = (short)f2bf(x1.z); f[7] = (short)f2bf(x1.w);
                a[t][h] = f;
            }
        }
        const unsigned char* gB = Ucb + (size_t)(cc * 32) * 2048 + lane * 16;
        bf16x8 c00 = *(const bf16x8*)(gB);
        bf16x8 c01 = *(const bf16x8*)(gB + 1024);
        bf16x8 c10 = *(const bf16x8*)(gB + 2048);
        bf16x8 c11 = *(const bf16x8*)(gB + 3072);
        float g = 0.f;
#pragma unroll 1
        for (int pt = 0; pt < 16; ++pt) {
            int npt = (pt < 15) ? (pt + 1) : 15;
            const unsigned char* nb = gB + (size_t)npt * 4096;
            bf16x8 n00 = *(const bf16x8*)(nb);
            bf16x8 n01 = *(const bf16x8*)(nb + 1024);
            bf16x8 n10 = *(const bf16x8*)(nb + 2048);
            bf16x8 n11 = *(const bf16x8*)(nb + 3072);
            f32x4 acc00 = {0.f,0.f,0.f,0.f}, acc01 = {0.f,0.f,0.f,0.f};
            f32x4 acc10 = {0.f,0.f,0.f,0.f}, acc11 = {0.f,0.f,0.f,0.f};
            acc00 = __builtin_amdgcn_mfma_f32_16x16x32_bf16(a[0][0], c00, acc00, 0, 0, 0);
            acc00 = __builtin_amdgcn_mfma_f32_16x16x32_bf16(a[0][1], c01, acc00, 0, 0, 0);
            acc10 = __builtin_amdgcn_mfma_f32_16x16x32_bf16(a[1][0], c00, acc10, 0, 0, 0);
            acc10 = __builtin_amdgcn_mfma_f32_16x16x32_bf16(a[1][1], c01, acc10, 0, 0, 0);
            acc01 = __builtin_amdgcn_mfma_f32_16x16x32_bf16(a[0][0], c10, acc01, 0, 0, 0);
            acc01 = __builtin_amdgcn_mfma_f32_16x16x32_bf16(a[0][1], c11, acc01, 0, 0, 0);
            acc11 = __builtin_amdgcn_mfma_f32_16x16x32_bf16(a[1][0], c10, acc11, 0, 0, 0);
            acc11 = __builtin_amdgcn_mfma_f32_16x16x32_bf16(a[1][1], c11, acc11, 0, 0, 0);
            // tile-sum is permutation-invariant -> C/D layout irrelevant;
            // dropping +eps*S (~2e-6 vs d~16) perturbs mi_org ~2e-7 << threshold
#pragma unroll
            for (int e = 0; e < 4; ++e) {
                float d0 = acc00[e]; g += d0 * __log2f(d0);
                float d1 = acc01[e]; g += d1 * __log2f(d1);
                float d2 = acc10[e]; g += d2 * __log2f(d2);
                float d3 = acc11[e]; g += d3 * __log2f(d3);
            }
            c00 = n00; c01 = n01; c10 = n10; c11 = n11;
        }
        float gw = wave_red(g);
        if (lane == 0) gshW[wvi] = gw;
        __syncthreads();
        if (tid == 0) {
            float gs = gshW[0] + gshW[1] + gshW[2] + gshW[3];
            atomicAdd(&Gacc[hb & 63], (double)gs);   // 32 blocks/shard
        }
    }

    // ---------- common tail: drain own atomics, 2-level sharded ticket ----------
    __builtin_amdgcn_s_waitcnt(0);
    __syncthreads();
    if (tid == 0) {
        flagS = 0;
        unsigned old = atomicAdd(&tickets[blk & 15], 1u);
        if (old == (NBLK_K2 / 16) - 1) {
            unsigned old2 = atomicAdd(&tickets[16], 1u);
            flagS = (old2 == 15u);
        }
    }
    __syncthreads();
    if (!flagS) return;

    // final: Aseg/Bseg/cpr/cpc from K1 (boundary-coherent); Gacc atomic-written.
    float*  Prx = (float*)smem;                      // 64 f32
    float*  Pry = (float*)(smem + 256);              // 64 f32
    double* sc  = (double*)(smem + 512);             // S,G,Uu,Vv
    double* red = (double*)(smem + 1024);            // 256 f64 (2048 B)
    if (tid < 64) {
        double sa = 0.0, sb = 0.0;
        for (int p = 0; p < 64; ++p) sa += (double)cpr[p * 64 + tid];
        for (int p = 0; p < 32; ++p) sb += (double)cpc[p * 64 + tid];
        red[tid] = sa * sb;
        Prx[tid] = 0.f; Pry[tid] = 0.f;
    }
    __syncthreads();
    if (tid == 0) {
        double s = 0.0;
        for (int k = 0; k < 64; ++k) s += red[k];
        sc[0] = s;
        double gg = 0.0;
        for (int k = 0; k < 64; ++k) gg += Gacc[k];
        sc[1] = gg;
    } else if (tid == 1) {
        double s = 0.0;
        for (int k = 64; k < 80; ++k) s += Gacc[k];
        sc[2] = s;
    } else if (tid == 2) {
        double s = 0.0;
        for (int k = 80; k < 96; ++k) s += Gacc[k];
        sc[3] = s;
    }
    __syncthreads();
    double S = sc[0];
    int p = tid >> 2, q0 = (tid & 3) * 16;
    float tloc[16];
    {
        float prow_sum = 0.f;
        for (int qi = 0; qi < 16; ++qi) {
            int q = q0 + qi;
            double s = 0.0;
            for (int k = 0; k < 64; ++k)
                s += (double)Aseg[p * 64 + k] * (double)Bseg[q * 64 + k];
            float t = (float)(s / S);
            tloc[qi] = t;
            prow_sum += t;
            atomicAdd(&Pry[q], t);
        }
        atomicAdd(&Prx[p], prow_sum);
    }
    __syncthreads();
    {
        const double EPSd = 1e-15;
        double part = 0.0;
        for (int qi = 0; qi < 16; ++qi) {
            double t = (double)tloc[qi];
            double txy = (double)Prx[p] * (double)Pry[q0 + qi];
            part += t * log((t + EPSd) / (txy + EPSd));
        }
        red[tid] = part;
    }
    __syncthreads();
    for (int s2 = 128; s2 > 0; s2 >>= 1) {
        if (tid < s2) red[tid] += red[tid + s2];
        __syncthreads();
    }
    if (tid == 0) {
        const double inv_ln2 = 1.4426950408889634;
        double mi_red = red[0] * inv_ln2;
        double G = sc[1], Uu = sc[2], Vv = sc[3];
        double log2S = log(S) * inv_ln2;
        double mi_org = G / S + log2S - (Uu + Vv) / S;
        double loss = log(1.0 + fabs(1.0 - mi_red / mi_org));
        out[0] = (float)loss;
    }
}

extern "C" void kernel_launch(void* const* d_in, const int* in_sizes, int n_in,
                              void* d_out, int out_size, void* d_ws, size_t ws_size,
                              hipStream_t stream) {
    const float* Ur = (const float*)d_in[0];
    const float* Uc = (const float*)d_in[1];
    float* out = (float*)d_out;
    char* ws = (char*)d_ws;
    unsigned short* Ucb = (unsigned short*)(ws + OFF_UCB);
    float* cpr   = (float*)(ws + OFF_CPR);
    float* cpc   = (float*)(ws + OFF_CPC);
    float* Aseg  = (float*)(ws + OFF_ASEG);
    float* Bseg  = (float*)(ws + OFF_BSEG);
    double* Gacc = (double*)(ws + OFF_GACC);
    unsigned* tickets = (unsigned*)(ws + OFF_TK);

    hipMemsetAsync(ws + OFF_ASEG, 0, ZERO_BYTES, stream);   // graph-capturable node
    k_prep<<<320, 256, 0, stream>>>(Ur, Uc, cpr, cpc, Ucb, Aseg, Bseg);
    k_main<<<NBLK_K2, 256, 0, stream>>>(Ur, Uc, (const unsigned char*)Ucb,
                                        cpr, cpc, Aseg, Bseg, Gacc, tickets, out);
}

// Round 14
// 178.793 us; speedup vs baseline: 1.1344x; 1.0854x over previous
//
#include <hip/hip_runtime.h>
#include <hip/hip_bf16.h>

#define N_INS 16384
#define N_ATT 8192
#define KDIM  64

typedef __attribute__((ext_vector_type(8))) short bf16x8;
typedef __attribute__((ext_vector_type(4))) float f32x4;

// ws layout (bytes):
// 0:       bf16 Ucb[8192*64] (1 MiB, fragment-order tiles)     [K1 writes all]
// 1048576: float cpr[64][64]                                    [K1 writes all]
// 1064960: float cpc[32][64]                                    [K1 writes all]
// 1073152: float Aseg[4096]   (atomic, zeroed by hipMemsetAsync)
// 1089536: float Bseg[4096]   (atomic, memset)
// 1105920: double Gacc[96]    ([0,64)=G, [64,80)=Uu, [80,96)=Vv; memset)
// 1106688: unsigned tickets[17] (16 shards + 1 global; memset)
#define OFF_UCB    0
#define OFF_CPR    1048576
#define OFF_CPC    1064960
#define OFF_ASEG   1073152
#define OFF_BSEG   1089536
#define OFF_GACC   1105920
#define OFF_TK     1106688
#define ZERO_BYTES 33604

#define NBLK_U     96             // K2 blocks [0,96): u-dot ([0,64)=Ur, [64,96)=Uc)
#define NBLK_HEAVY 2048           // K2 blocks [96, 2144)
#define NBLK_K2    (NBLK_U + NBLK_HEAVY)     // 2144 = 16 * 134

__device__ __forceinline__ unsigned short f2bf(float x) {
    unsigned u = __float_as_uint(x);
    u = (u + 0x7FFFu + ((u >> 16) & 1u)) >> 16;   // RNE
    return (unsigned short)u;
}

__device__ __forceinline__ float wave_red(float v) {
#pragma unroll
    for (int o = 32; o > 0; o >>= 1) v += __shfl_down(v, o, 64);
    return v;
}

// async 16B global -> LDS DMA (dest = wave-uniform base + lane*16)
typedef __attribute__((address_space(3))) unsigned int as3_u32;
typedef const __attribute__((address_space(1))) unsigned int as1_u32;
__device__ __forceinline__ void stage16(void* l, const void* g) {
    __builtin_amdgcn_global_load_lds((as1_u32*)g, (as3_u32*)l, 16, 0, 0);
}

// ---- K1: convert + colsums + argmax/segment-sums (unchanged from R13) ----
// blocks [0,128):   convert Uc->bf16 fragment tiles (store-coalesced)
// blocks [128,192): Ur colsums (256 rows)  -> cpr[b]
// blocks [192,224): Uc colsums (256 rows)  -> cpc[b]
// blocks [224,288): Ur argmax+segsum (256 rows) -> atomic fold into Aseg
// blocks [288,320): Uc argmax+segsum (256 rows) -> atomic fold into Bseg
__global__ __launch_bounds__(256)
void k_prep(const float* __restrict__ Ur, const float* __restrict__ Uc,
            float* __restrict__ cpr, float* __restrict__ cpc,
            unsigned short* __restrict__ Ucb,
            float* __restrict__ Aseg, float* __restrict__ Bseg) {
    __shared__ __align__(16) unsigned char smem[17408];
    int blk = blockIdx.x, tid = threadIdx.x;
    if (blk < 128) {
        // Ucb tile t (2KB, rows 16t..16t+15), chunk o at t*2048+o*16;
        // o<64 -> q=o>>4,m=o&15 ; o>=64 -> q=4+((o-64)>>4), m=(o-64)&15.
        int gid = blk * 256 + tid;
        for (int c = gid; c < N_ATT * 8; c += 32768) {
            int t = c >> 7, o = c & 127;
            int q, m;
            if (o < 64) { q = o >> 4; m = o & 15; }
            else        { q = 4 + ((o - 64) >> 4); m = (o - 64) & 15; }
            int r = t * 16 + m;
            const float4* src = (const float4*)(Uc + (size_t)r * 64 + q * 8);
            float4 x0 = src[0], x1 = src[1];
            uint4 v;
            v.x = (unsigned)f2bf(x0.x) | ((unsigned)f2bf(x0.y) << 16);
            v.y = (unsigned)f2bf(x0.z) | ((unsigned)f2bf(x0.w) << 16);
            v.z = (unsigned)f2bf(x1.x) | ((unsigned)f2bf(x1.y) << 16);
            v.w = (unsigned)f2bf(x1.z) | ((unsigned)f2bf(x1.w) << 16);
            *(uint4*)((unsigned char*)Ucb + (size_t)c * 16) = v;
        }
        return;
    }
    if (blk < 224) {
        float* cs2 = (float*)smem;
        bool isUr = blk < 192;
        int b = isUr ? (blk - 128) : (blk - 192);
        const float* base = (isUr ? Ur : Uc) + (size_t)b * 256 * KDIM;
        float* dst = (isUr ? cpr : cpc) + b * 64;
        int col = tid & 63, r0 = tid >> 6;
        float s = 0.f;
        for (int r = r0; r < 256; r += 4) s += base[r * KDIM + col];
        cs2[tid] = s;
        __syncthreads();
        if (tid < 64) dst[tid] = cs2[tid] + cs2[tid + 64] + cs2[tid + 128] + cs2[tid + 192];
        return;
    }
    float* Part = (float*)smem;                      // 4096 f32
    int*   bins = (int*)(smem + 16384);              // 256 ints
    bool isUr = blk < 288;
    int b = isUr ? (blk - 224) : (blk - 288);
    const float* M = isUr ? Ur : Uc;
    float* Seg = isUr ? Aseg : Bseg;
    int base_row = b * 256;
    int wvi = tid >> 6, lane = tid & 63;

    for (int i = tid; i < 4096; i += 256) Part[i] = 0.f;
    __syncthreads();
    {   // phase 1: row-per-thread argmax (pure VALU)
        const float* rp = M + (size_t)(base_row + tid) * KDIM;
        float best = -1e30f; int bidx = 0;
#pragma unroll
        for (int k = 0; k < 64; k += 4) {
            float4 v = *(const float4*)(rp + k);
            if (v.x > best) { best = v.x; bidx = k; }
            if (v.y > best) { best = v.y; bidx = k + 1; }
            if (v.z > best) { best = v.z; bidx = k + 2; }
            if (v.w > best) { best = v.w; bidx = k + 3; }
        }
        bins[tid] = bidx;
    }
    __syncthreads();
    {   // phase 2: one fire-and-forget ds_add per row per wave
        int r0 = wvi * 64;
        const float* Mb = M + (size_t)(base_row + r0) * 64 + lane;
#pragma unroll 4
        for (int r = 0; r < 64; ++r) {
            int bb = bins[r0 + r];
            float val = Mb[(size_t)r * 64];
            atomicAdd(&Part[bb * 64 + lane], val);
        }
    }
    __syncthreads();
    for (int i = tid; i < 4096; i += 256)
        atomicAdd(&Seg[i], Part[i]);
}

// ---- K2: u-dots (96) + heavy (2048, async-LDS B pipeline) + ticketed final ----
// R13 post-mortem: heavy stalled 6x its 18.5us VALU floor — per-WAVE register
// prefetch left each wave exposed to L2 latency and 4x-redundant B loads.
// Now: per-BLOCK global_load_lds staging (1 instr/wave/iter), double-buffered
// 4KB pairs, one barrier/iter, fragments via ds_read_b128 (2-way bank = free).
__global__ __launch_bounds__(256)
void k_main(const float* __restrict__ Ur, const float* __restrict__ Uc,
            const unsigned char* __restrict__ Ucb,
            const float* __restrict__ cpr, const float* __restrict__ cpc,
            const float* __restrict__ Aseg, const float* __restrict__ Bseg,
            double* __restrict__ Gacc, unsigned* __restrict__ tickets,
            float* __restrict__ out) {
    __shared__ __align__(16) unsigned char smem[8464];
    __shared__ int flagS;
    int tid = threadIdx.x, blk = blockIdx.x;
    int wvi = tid >> 6, lane = tid & 63;

    if (blk < NBLK_U) {
        // ---------- u-dot: u=row.colsum(other), Gacc += u*log2(u) ----------
        float* wv = (float*)smem;
        bool isUr = blk < 64;
        int b = isUr ? blk : (blk - 64);
        const float* M = isUr ? Ur : Uc;
        int base_row = b * 256;
        if (tid < 64) {
            const float* cpw = isUr ? cpc : cpr;
            int nbw = isUr ? 32 : 64;
            float s = 0.f;
            for (int p = 0; p < nbw; ++p) s += cpw[p * 64 + tid];
            wv[tid] = s;
        }
        __syncthreads();
        const float* rp = M + (size_t)(base_row + tid) * KDIM;
        float u = 0.f;
#pragma unroll
        for (int k = 0; k < 64; k += 4) {
            float4 v = *(const float4*)(rp + k);
            u += v.x * wv[k] + v.y * wv[k + 1] + v.z * wv[k + 2] + v.w * wv[k + 3];
        }
        float pw = wave_red(u * __log2f(u));
        if (lane == 0)
            atomicAdd(&Gacc[(isUr ? 64 : 80) + (b & 15)], (double)pw);
    } else {
        // ---------- heavy: G += d*log2(d), MFMA + async-LDS double buffer ----------
        unsigned char* bufs = smem;                  // 2 x 4096 B
        float* gshW = (float*)(smem + 8192);
        int hb = blk - NBLK_U;
        int quad = lane >> 4, m = lane & 15;
        int rb = hb & 127, cc = hb >> 7;
        int row0 = rb * 128 + wvi * 32;
        bf16x8 a[2][2];
#pragma unroll
        for (int t = 0; t < 2; ++t) {
            int ridx = row0 + t * 16 + m;
            const float* rp = Ur + (size_t)ridx * 64 + quad * 8;
#pragma unroll
            for (int h = 0; h < 2; ++h) {
                const float* rph = rp + h * 32;
                float4 x0 = *(const float4*)rph;
                float4 x1 = *(const float4*)(rph + 4);
                bf16x8 f;
                f[0] = (short)f2bf(x0.x); f[1] = (short)f2bf(x0.y);
                f[2] = (short)f2bf(x0.z); f[3] = (short)f2bf(x0.w);
                f[4] = (short)f2bf(x1.x); f[5] = (short)f2bf(x1.y);
                f[6] = (short)f2bf(x1.z); f[7] = (short)f2bf(x1.w);
                a[t][h] = f;
            }
        }
        // 16 pairs x 4KB; wave wvi stages its 1KB chunk of each pair
        const unsigned char* gB = Ucb + (size_t)(cc * 32) * 2048;
        int soff = wvi * 1024 + lane * 16;
        stage16(bufs + soff, gB + soff);             // pair 0 -> buf 0
        int loff = lane * 16;
        float g = 0.f;
#pragma unroll 1
        for (int pt = 0; pt < 16; ++pt) {
            __syncthreads();   // pair pt staged (vmcnt drained); pt-1 reads done
            if (pt < 15)
                stage16(bufs + (((pt + 1) & 1) << 12) + soff,
                        gB + (size_t)(pt + 1) * 4096 + soff);
            const unsigned char* bb = bufs + ((pt & 1) << 12);
            bf16x8 c00 = *(const bf16x8*)(bb + loff);
            bf16x8 c01 = *(const bf16x8*)(bb + 1024 + loff);
            bf16x8 c10 = *(const bf16x8*)(bb + 2048 + loff);
            bf16x8 c11 = *(const bf16x8*)(bb + 3072 + loff);
            f32x4 acc00 = {0.f,0.f,0.f,0.f}, acc01 = {0.f,0.f,0.f,0.f};
            f32x4 acc10 = {0.f,0.f,0.f,0.f}, acc11 = {0.f,0.f,0.f,0.f};
            acc00 = __builtin_amdgcn_mfma_f32_16x16x32_bf16(a[0][0], c00, acc00, 0, 0, 0);
            acc00 = __builtin_amdgcn_mfma_f32_16x16x32_bf16(a[0][1], c01, acc00, 0, 0, 0);
            acc10 = __builtin_amdgcn_mfma_f32_16x16x32_bf16(a[1][0], c00, acc10, 0, 0, 0);
            acc10 = __builtin_amdgcn_mfma_f32_16x16x32_bf16(a[1][1], c01, acc10, 0, 0, 0);
            acc01 = __builtin_amdgcn_mfma_f32_16x16x32_bf16(a[0][0], c10, acc01, 0, 0, 0);
            acc01 = __builtin_amdgcn_mfma_f32_16x16x32_bf16(a[0][1], c11, acc01, 0, 0, 0);
            acc11 = __builtin_amdgcn_mfma_f32_16x16x32_bf16(a[1][0], c10, acc11, 0, 0, 0);
            acc11 = __builtin_amdgcn_mfma_f32_16x16x32_bf16(a[1][1], c11, acc11, 0, 0, 0);
            // tile-sum is permutation-invariant -> C/D layout irrelevant;
            // dropping +eps*S (~2e-6 vs d~16) perturbs mi_org ~2e-7 << threshold
#pragma unroll
            for (int e = 0; e < 4; ++e) {
                float d0 = acc00[e]; g += d0 * __log2f(d0);
                float d1 = acc01[e]; g += d1 * __log2f(d1);
                float d2 = acc10[e]; g += d2 * __log2f(d2);
                float d3 = acc11[e]; g += d3 * __log2f(d3);
            }
        }
        float gw = wave_red(g);
        if (lane == 0) gshW[wvi] = gw;
        __syncthreads();
        if (tid == 0) {
            float gs = gshW[0] + gshW[1] + gshW[2] + gshW[3];
            atomicAdd(&Gacc[hb & 63], (double)gs);   // 32 blocks/shard
        }
    }

    // ---------- common tail: drain own atomics, 2-level sharded ticket ----------
    __builtin_amdgcn_s_waitcnt(0);
    __syncthreads();
    if (tid == 0) {
        flagS = 0;
        unsigned old = atomicAdd(&tickets[blk & 15], 1u);
        if (old == (NBLK_K2 / 16) - 1) {
            unsigned old2 = atomicAdd(&tickets[16], 1u);
            flagS = (old2 == 15u);
        }
    }
    __syncthreads();
    if (!flagS) return;

    // final: Aseg/Bseg/cpr/cpc from K1 (boundary-coherent); Gacc atomic-written.
    float*  Prx = (float*)smem;                      // 64 f32
    float*  Pry = (float*)(smem + 256);              // 64 f32
    double* sc  = (double*)(smem + 512);             // S,G,Uu,Vv
    double* red = (double*)(smem + 1024);            // 256 f64
    if (tid < 64) {
        double sa = 0.0, sb = 0.0;
        for (int p = 0; p < 64; ++p) sa += (double)cpr[p * 64 + tid];
        for (int p = 0; p < 32; ++p) sb += (double)cpc[p * 64 + tid];
        red[tid] = sa * sb;
        Prx[tid] = 0.f; Pry[tid] = 0.f;
    }
    __syncthreads();
    if (tid == 0) {
        double s = 0.0;
        for (int k = 0; k < 64; ++k) s += red[k];
        sc[0] = s;
        double gg = 0.0;
        for (int k = 0; k < 64; ++k) gg += Gacc[k];
        sc[1] = gg;
    } else if (tid == 1) {
        double s = 0.0;
        for (int k = 64; k < 80; ++k) s += Gacc[k];
        sc[2] = s;
    } else if (tid == 2) {
        double s = 0.0;
        for (int k = 80; k < 96; ++k) s += Gacc[k];
        sc[3] = s;
    }
    __syncthreads();
    double S = sc[0];
    int p = tid >> 2, q0 = (tid & 3) * 16;
    float tloc[16];
    {
        float prow_sum = 0.f;
        for (int qi = 0; qi < 16; ++qi) {
            int q = q0 + qi;
            double s = 0.0;
            for (int k = 0; k < 64; ++k)
                s += (double)Aseg[p * 64 + k] * (double)Bseg[q * 64 + k];
            float t = (float)(s / S);
            tloc[qi] = t;
            prow_sum += t;
            atomicAdd(&Pry[q], t);
        }
        atomicAdd(&Prx[p], prow_sum);
    }
    __syncthreads();
    {
        const double EPSd = 1e-15;
        double part = 0.0;
        for (int qi = 0; qi < 16; ++qi) {
            double t = (double)tloc[qi];
            double txy = (double)Prx[p] * (double)Pry[q0 + qi];
            part += t * log((t + EPSd) / (txy + EPSd));
        }
        red[tid] = part;
    }
    __syncthreads();
    for (int s2 = 128; s2 > 0; s2 >>= 1) {
        if (tid < s2) red[tid] += red[tid + s2];
        __syncthreads();
    }
    if (tid == 0) {
        const double inv_ln2 = 1.4426950408889634;
        double mi_red = red[0] * inv_ln2;
        double G = sc[1], Uu = sc[2], Vv = sc[3];
        double log2S = log(S) * inv_ln2;
        double mi_org = G / S + log2S - (Uu + Vv) / S;
        double loss = log(1.0 + fabs(1.0 - mi_red / mi_org));
        out[0] = (float)loss;
    }
}

extern "C" void kernel_launch(void* const* d_in, const int* in_sizes, int n_in,
                              void* d_out, int out_size, void* d_ws, size_t ws_size,
                              hipStream_t stream) {
    const float* Ur = (const float*)d_in[0];
    const float* Uc = (const float*)d_in[1];
    float* out = (float*)d_out;
    char* ws = (char*)d_ws;
    unsigned short* Ucb = (unsigned short*)(ws + OFF_UCB);
    float* cpr   = (float*)(ws + OFF_CPR);
    float* cpc   = (float*)(ws + OFF_CPC);
    float* Aseg  = (float*)(ws + OFF_ASEG);
    float* Bseg  = (float*)(ws + OFF_BSEG);
    double* Gacc = (double*)(ws + OFF_GACC);
    unsigned* tickets = (unsigned*)(ws + OFF_TK);

    hipMemsetAsync(ws + OFF_ASEG, 0, ZERO_BYTES, stream);
    k_prep<<<320, 256, 0, stream>>>(Ur, Uc, cpr, cpc, Ucb, Aseg, Bseg);
    k_main<<<NBLK_K2, 256, 0, stream>>>(Ur, Uc, (const unsigned char*)Ucb,
                                        cpr, cpc, Aseg, Bseg, Gacc, tickets, out);
}

// Round 15
// 167.704 us; speedup vs baseline: 1.2094x; 1.0661x over previous
//
#include <hip/hip_runtime.h>
#include <hip/hip_bf16.h>

#define N_INS 16384
#define N_ATT 8192
#define KDIM  64

typedef __attribute__((ext_vector_type(8))) short bf16x8;
typedef __attribute__((ext_vector_type(4))) float f32x4;

// ws layout (bytes):
// 0:       bf16 Ucb[8192*64] (1 MiB, fragment-order tiles)     [K1 writes all]
// 1048576: float cpr[64][64]                                    [K1 writes all]
// 1064960: float cpc[32][64]                                    [K1 writes all]
// 1073152: float Aseg[4096]   (atomic, zeroed by hipMemsetAsync)
// 1089536: float Bseg[4096]   (atomic, memset)
// 1105920: double Gacc[96]    ([0,64)=G, [64,80)=Uu, [80,96)=Vv; memset)
// 1106688: unsigned tickets[272]  (shard s at [s*16] -> one 64B line each;
//                                  global at [256]; memset)
#define OFF_UCB    0
#define OFF_CPR    1048576
#define OFF_CPC    1064960
#define OFF_ASEG   1073152
#define OFF_BSEG   1089536
#define OFF_GACC   1105920
#define OFF_TK     1106688
#define ZERO_BYTES 34624

#define NBLK_U     96             // K2 blocks [0,96): u-dot ([0,64)=Ur, [64,96)=Uc)
#define NBLK_HEAVY 2048           // K2 blocks [96, 2144)
#define NBLK_K2    (NBLK_U + NBLK_HEAVY)     // 2144 = 16 * 134

__device__ __forceinline__ unsigned short f2bf(float x) {
    unsigned u = __float_as_uint(x);
    u = (u + 0x7FFFu + ((u >> 16) & 1u)) >> 16;   // RNE
    return (unsigned short)u;
}

__device__ __forceinline__ float wave_red(float v) {
#pragma unroll
    for (int o = 32; o > 0; o >>= 1) v += __shfl_down(v, o, 64);
    return v;
}

// async 16B global -> LDS DMA (dest = wave-uniform base + lane*16)
typedef __attribute__((address_space(3))) unsigned int as3_u32;
typedef const __attribute__((address_space(1))) unsigned int as1_u32;
__device__ __forceinline__ void stage16(void* l, const void* g) {
    __builtin_amdgcn_global_load_lds((as1_u32*)g, (as3_u32*)l, 16, 0, 0);
}

// ---- K1: convert + colsums + argmax/segment-sums (unchanged from R14) ----
// blocks [0,128):   convert Uc->bf16 fragment tiles (store-coalesced)
// blocks [128,192): Ur colsums (256 rows)  -> cpr[b]
// blocks [192,224): Uc colsums (256 rows)  -> cpc[b]
// blocks [224,288): Ur argmax+segsum (256 rows) -> atomic fold into Aseg
// blocks [288,320): Uc argmax+segsum (256 rows) -> atomic fold into Bseg
__global__ __launch_bounds__(256)
void k_prep(const float* __restrict__ Ur, const float* __restrict__ Uc,
            float* __restrict__ cpr, float* __restrict__ cpc,
            unsigned short* __restrict__ Ucb,
            float* __restrict__ Aseg, float* __restrict__ Bseg) {
    __shared__ __align__(16) unsigned char smem[17408];
    int blk = blockIdx.x, tid = threadIdx.x;
    if (blk < 128) {
        // Ucb tile t (2KB, rows 16t..16t+15), chunk o at t*2048+o*16;
        // o<64 -> q=o>>4,m=o&15 ; o>=64 -> q=4+((o-64)>>4), m=(o-64)&15.
        int gid = blk * 256 + tid;
        for (int c = gid; c < N_ATT * 8; c += 32768) {
            int t = c >> 7, o = c & 127;
            int q, m;
            if (o < 64) { q = o >> 4; m = o & 15; }
            else        { q = 4 + ((o - 64) >> 4); m = (o - 64) & 15; }
            int r = t * 16 + m;
            const float4* src = (const float4*)(Uc + (size_t)r * 64 + q * 8);
            float4 x0 = src[0], x1 = src[1];
            uint4 v;
            v.x = (unsigned)f2bf(x0.x) | ((unsigned)f2bf(x0.y) << 16);
            v.y = (unsigned)f2bf(x0.z) | ((unsigned)f2bf(x0.w) << 16);
            v.z = (unsigned)f2bf(x1.x) | ((unsigned)f2bf(x1.y) << 16);
            v.w = (unsigned)f2bf(x1.z) | ((unsigned)f2bf(x1.w) << 16);
            *(uint4*)((unsigned char*)Ucb + (size_t)c * 16) = v;
        }
        return;
    }
    if (blk < 224) {
        float* cs2 = (float*)smem;
        bool isUr = blk < 192;
        int b = isUr ? (blk - 128) : (blk - 192);
        const float* base = (isUr ? Ur : Uc) + (size_t)b * 256 * KDIM;
        float* dst = (isUr ? cpr : cpc) + b * 64;
        int col = tid & 63, r0 = tid >> 6;
        float s = 0.f;
        for (int r = r0; r < 256; r += 4) s += base[r * KDIM + col];
        cs2[tid] = s;
        __syncthreads();
        if (tid < 64) dst[tid] = cs2[tid] + cs2[tid + 64] + cs2[tid + 128] + cs2[tid + 192];
        return;
    }
    float* Part = (float*)smem;                      // 4096 f32
    int*   bins = (int*)(smem + 16384);              // 256 ints
    bool isUr = blk < 288;
    int b = isUr ? (blk - 224) : (blk - 288);
    const float* M = isUr ? Ur : Uc;
    float* Seg = isUr ? Aseg : Bseg;
    int base_row = b * 256;
    int wvi = tid >> 6, lane = tid & 63;

    for (int i = tid; i < 4096; i += 256) Part[i] = 0.f;
    __syncthreads();
    {   // phase 1: row-per-thread argmax (pure VALU)
        const float* rp = M + (size_t)(base_row + tid) * KDIM;
        float best = -1e30f; int bidx = 0;
#pragma unroll
        for (int k = 0; k < 64; k += 4) {
            float4 v = *(const float4*)(rp + k);
            if (v.x > best) { best = v.x; bidx = k; }
            if (v.y > best) { best = v.y; bidx = k + 1; }
            if (v.z > best) { best = v.z; bidx = k + 2; }
            if (v.w > best) { best = v.w; bidx = k + 3; }
        }
        bins[tid] = bidx;
    }
    __syncthreads();
    {   // phase 2: one fire-and-forget ds_add per row per wave
        int r0 = wvi * 64;
        const float* Mb = M + (size_t)(base_row + r0) * 64 + lane;
#pragma unroll 4
        for (int r = 0; r < 64; ++r) {
            int bb = bins[r0 + r];
            float val = Mb[(size_t)r * 64];
            atomicAdd(&Part[bb * 64 + lane], val);
        }
    }
    __syncthreads();
    for (int i = tid; i < 4096; i += 256)
        atomicAdd(&Seg[i], Part[i]);
}

// ---- K2: u-dots (96) + heavy (2048, async-LDS, 2 pairs/barrier) + final ----
// R14 post-mortem: k_main stuck in the 93-132us band across 3 heavy rewrites;
// tickets[16] shards all lived in ONE 64B cache line -> 2144 block-retirement
// RMWs serialized at the coherence point (~25-40ns each = 50-85us floor).
// Fix 1: each shard on its own 64B line. Fix 2: heavy stages 8KB (2 pairs)
// per barrier -> 8 barriers/block instead of 16, ~1200cyc compute between
// barriers fully covers the staging latency (even HBM).
__global__ __launch_bounds__(256)
void k_main(const float* __restrict__ Ur, const float* __restrict__ Uc,
            const unsigned char* __restrict__ Ucb,
            const float* __restrict__ cpr, const float* __restrict__ cpc,
            const float* __restrict__ Aseg, const float* __restrict__ Bseg,
            double* __restrict__ Gacc, unsigned* __restrict__ tickets,
            float* __restrict__ out) {
    __shared__ __align__(16) unsigned char smem[16400];
    __shared__ int flagS;
    int tid = threadIdx.x, blk = blockIdx.x;
    int wvi = tid >> 6, lane = tid & 63;

    if (blk < NBLK_U) {
        // ---------- u-dot: u=row.colsum(other), Gacc += u*log2(u) ----------
        float* wv = (float*)smem;
        bool isUr = blk < 64;
        int b = isUr ? blk : (blk - 64);
        const float* M = isUr ? Ur : Uc;
        int base_row = b * 256;
        if (tid < 64) {
            const float* cpw = isUr ? cpc : cpr;
            int nbw = isUr ? 32 : 64;
            float s = 0.f;
            for (int p = 0; p < nbw; ++p) s += cpw[p * 64 + tid];
            wv[tid] = s;
        }
        __syncthreads();
        const float* rp = M + (size_t)(base_row + tid) * KDIM;
        float u = 0.f;
#pragma unroll
        for (int k = 0; k < 64; k += 4) {
            float4 v = *(const float4*)(rp + k);
            u += v.x * wv[k] + v.y * wv[k + 1] + v.z * wv[k + 2] + v.w * wv[k + 3];
        }
        float pw = wave_red(u * __log2f(u));
        if (lane == 0)
            atomicAdd(&Gacc[(isUr ? 64 : 80) + (b & 15)], (double)pw);
    } else {
        // ---------- heavy: G += d*log2(d), MFMA, 2-pair double-buffered LDS ----------
        unsigned char* bufs = smem;                  // 2 x 8192 B
        float* gshW = (float*)(smem + 16384);
        int hb = blk - NBLK_U;
        int quad = lane >> 4, m = lane & 15;
        int rb = hb & 127, cc = hb >> 7;
        int row0 = rb * 128 + wvi * 32;
        bf16x8 a[2][2];
#pragma unroll
        for (int t = 0; t < 2; ++t) {
            int ridx = row0 + t * 16 + m;
            const float* rp = Ur + (size_t)ridx * 64 + quad * 8;
#pragma unroll
            for (int h = 0; h < 2; ++h) {
                const float* rph = rp + h * 32;
                float4 x0 = *(const float4*)rph;
                float4 x1 = *(const float4*)(rph + 4);
                bf16x8 f;
                f[0] = (short)f2bf(x0.x); f[1] = (short)f2bf(x0.y);
                f[2] = (short)f2bf(x0.z); f[3] = (short)f2bf(x0.w);
                f[4] = (short)f2bf(x1.x); f[5] = (short)f2bf(x1.y);
                f[6] = (short)f2bf(x1.z); f[7] = (short)f2bf(x1.w);
                a[t][h] = f;
            }
        }
        // 8 groups x 8KB (2 pairs each); wave stages its 2KB of each group
        const unsigned char* gB = Ucb + (size_t)(cc * 32) * 2048;
        int soff = wvi * 2048 + lane * 16;
        stage16(bufs + soff, gB + soff);
        stage16(bufs + soff + 1024, gB + soff + 1024);
        int loff = lane * 16;
        float g = 0.f;
#pragma unroll 1
        for (int pg = 0; pg < 8; ++pg) {
            __syncthreads();   // group pg staged (vmcnt drained); pg-1 reads done
            if (pg < 7) {
                const unsigned char* gn = gB + (size_t)(pg + 1) * 8192;
                unsigned char* bn = bufs + (((pg + 1) & 1) << 13);
                stage16(bn + soff, gn + soff);
                stage16(bn + soff + 1024, gn + soff + 1024);
            }
            const unsigned char* bg = bufs + ((pg & 1) << 13);
#pragma unroll
            for (int p = 0; p < 2; ++p) {
                const unsigned char* bb = bg + p * 4096;
                bf16x8 c00 = *(const bf16x8*)(bb + loff);
                bf16x8 c01 = *(const bf16x8*)(bb + 1024 + loff);
                bf16x8 c10 = *(const bf16x8*)(bb + 2048 + loff);
                bf16x8 c11 = *(const bf16x8*)(bb + 3072 + loff);
                f32x4 acc00 = {0.f,0.f,0.f,0.f}, acc01 = {0.f,0.f,0.f,0.f};
                f32x4 acc10 = {0.f,0.f,0.f,0.f}, acc11 = {0.f,0.f,0.f,0.f};
                acc00 = __builtin_amdgcn_mfma_f32_16x16x32_bf16(a[0][0], c00, acc00, 0, 0, 0);
                acc00 = __builtin_amdgcn_mfma_f32_16x16x32_bf16(a[0][1], c01, acc00, 0, 0, 0);
                acc10 = __builtin_amdgcn_mfma_f32_16x16x32_bf16(a[1][0], c00, acc10, 0, 0, 0);
                acc10 = __builtin_amdgcn_mfma_f32_16x16x32_bf16(a[1][1], c01, acc10, 0, 0, 0);
                acc01 = __builtin_amdgcn_mfma_f32_16x16x32_bf16(a[0][0], c10, acc01, 0, 0, 0);
                acc01 = __builtin_amdgcn_mfma_f32_16x16x32_bf16(a[0][1], c11, acc01, 0, 0, 0);
                acc11 = __builtin_amdgcn_mfma_f32_16x16x32_bf16(a[1][0], c10, acc11, 0, 0, 0);
                acc11 = __builtin_amdgcn_mfma_f32_16x16x32_bf16(a[1][1], c11, acc11, 0, 0, 0);
                // tile-sum is permutation-invariant -> C/D layout irrelevant;
                // dropping +eps*S (~2e-6 vs d~16) perturbs mi_org ~2e-7 << thresh
#pragma unroll
                for (int e = 0; e < 4; ++e) {
                    float d0 = acc00[e]; g += d0 * __log2f(d0);
                    float d1 = acc01[e]; g += d1 * __log2f(d1);
                    float d2 = acc10[e]; g += d2 * __log2f(d2);
                    float d3 = acc11[e]; g += d3 * __log2f(d3);
                }
            }
        }
        float gw = wave_red(g);
        if (lane == 0) gshW[wvi] = gw;
        __syncthreads();
        if (tid == 0) {
            float gs = gshW[0] + gshW[1] + gshW[2] + gshW[3];
            atomicAdd(&Gacc[hb & 63], (double)gs);   // 32 blocks/shard, 8 lines
        }
    }

    // ---------- common tail: drain own atomics, line-padded sharded ticket ----------
    __builtin_amdgcn_s_waitcnt(0);                   // Gacc atomic acked before ticket
    __syncthreads();
    if (tid == 0) {
        flagS = 0;
        unsigned old = atomicAdd(&tickets[(blk & 15) << 4], 1u);  // own 64B line
        if (old == (NBLK_K2 / 16) - 1) {
            unsigned old2 = atomicAdd(&tickets[256], 1u);
            flagS = (old2 == 15u);
        }
    }
    __syncthreads();
    if (!flagS) return;

    // final: Aseg/Bseg/cpr/cpc from K1 (boundary-coherent); Gacc atomic-written.
    float*  Prx = (float*)smem;                      // 64 f32
    float*  Pry = (float*)(smem + 256);              // 64 f32
    double* sc  = (double*)(smem + 512);             // S,G,Uu,Vv
    double* red = (double*)(smem + 1024);            // 256 f64
    if (tid < 64) {
        double sa = 0.0, sb = 0.0;
        for (int p = 0; p < 64; ++p) sa += (double)cpr[p * 64 + tid];
        for (int p = 0; p < 32; ++p) sb += (double)cpc[p * 64 + tid];
        red[tid] = sa * sb;
        Prx[tid] = 0.f; Pry[tid] = 0.f;
    }
    __syncthreads();
    if (tid == 0) {
        double s = 0.0;
        for (int k = 0; k < 64; ++k) s += red[k];
        sc[0] = s;
        double gg = 0.0;
        for (int k = 0; k < 64; ++k) gg += Gacc[k];
        sc[1] = gg;
    } else if (tid == 1) {
        double s = 0.0;
        for (int k = 64; k < 80; ++k) s += Gacc[k];
        sc[2] = s;
    } else if (tid == 2) {
        double s = 0.0;
        for (int k = 80; k < 96; ++k) s += Gacc[k];
        sc[3] = s;
    }
    __syncthreads();
    double S = sc[0];
    int p = tid >> 2, q0 = (tid & 3) * 16;
    float tloc[16];
    {
        float prow_sum = 0.f;
        for (int qi = 0; qi < 16; ++qi) {
            int q = q0 + qi;
            double s = 0.0;
            for (int k = 0; k < 64; ++k)
                s += (double)Aseg[p * 64 + k] * (double)Bseg[q * 64 + k];
            float t = (float)(s / S);
            tloc[qi] = t;
            prow_sum += t;
            atomicAdd(&Pry[q], t);
        }
        atomicAdd(&Prx[p], prow_sum);
    }
    __syncthreads();
    {
        const double EPSd = 1e-15;
        double part = 0.0;
        for (int qi = 0; qi < 16; ++qi) {
            double t = (double)tloc[qi];
            double txy = (double)Prx[p] * (double)Pry[q0 + qi];
            part += t * log((t + EPSd) / (txy + EPSd));
        }
        red[tid] = part;
    }
    __syncthreads();
    for (int s2 = 128; s2 > 0; s2 >>= 1) {
        if (tid < s2) red[tid] += red[tid + s2];
        __syncthreads();
    }
    if (tid == 0) {
        const double inv_ln2 = 1.4426950408889634;
        double mi_red = red[0] * inv_ln2;
        double G = sc[1], Uu = sc[2], Vv = sc[3];
        double log2S = log(S) * inv_ln2;
        double mi_org = G / S + log2S - (Uu + Vv) / S;
        double loss = log(1.0 + fabs(1.0 - mi_red / mi_org));
        out[0] = (float)loss;
    }
}

extern "C" void kernel_launch(void* const* d_in, const int* in_sizes, int n_in,
                              void* d_out, int out_size, void* d_ws, size_t ws_size,
                              hipStream_t stream) {
    const float* Ur = (const float*)d_in[0];
    const float* Uc = (const float*)d_in[1];
    float* out = (float*)d_out;
    char* ws = (char*)d_ws;
    unsigned short* Ucb = (unsigned short*)(ws + OFF_UCB);
    float* cpr   = (float*)(ws + OFF_CPR);
    float* cpc   = (float*)(ws + OFF_CPC);
    float* Aseg  = (float*)(ws + OFF_ASEG);
    float* Bseg  = (float*)(ws + OFF_BSEG);
    double* Gacc = (double*)(ws + OFF_GACC);
    unsigned* tickets = (unsigned*)(ws + OFF_TK);

    hipMemsetAsync(ws + OFF_ASEG, 0, ZERO_BYTES, stream);
    k_prep<<<320, 256, 0, stream>>>(Ur, Uc, cpr, cpc, Ucb, Aseg, Bseg);
    k_main<<<NBLK_K2, 256, 0, stream>>>(Ur, Uc, (const unsigned char*)Ucb,
                                        cpr, cpc, Aseg, Bseg, Gacc, tickets, out);
}

// Round 17
// 165.452 us; speedup vs baseline: 1.2259x; 1.0136x over previous
//
#include <hip/hip_runtime.h>
#include <hip/hip_bf16.h>

#define N_INS 16384
#define N_ATT 8192
#define KDIM  64

typedef __attribute__((ext_vector_type(8))) short bf16x8;
typedef __attribute__((ext_vector_type(4))) float f32x4;

// ws layout (bytes)  — R16 BUG: segparts ends at 1073152+1572864=2646016 but
// Aseg was placed at 2645504 -> 512B overlap corrupted Aseg[0..127]. Fixed map:
// 0:       bf16 Ucb[8192*64] (1 MiB, fragment-order tiles)     [K1 writes all]
// 1048576: float cpr[64][64]                                    [K1 writes all]
// 1064960: float cpc[32][64]                                    [K1 writes all]
// 1073152: float segparts[96][4096] (1.5 MiB, ends 2646016)     [K1 writes all]
// 2646016: float Aseg[4096]   (zeroed by K1; atomic-folded in K2)
// 2662400: float Bseg[4096]   (zeroed by K1; atomic-folded in K2)
// 2678784: double Gacc[96]    ([0,64)=G, [64,80)=Uu, [80,96)=Vv; K1 zeroes)
// 2679552: unsigned tickets[272] (shard s at [s*16], global at [256]; K1 zeroes)
#define OFF_UCB    0
#define OFF_CPR    1048576
#define OFF_CPC    1064960
#define OFF_SEGP   1073152
#define OFF_ASEG   2646016
#define OFF_BSEG   2662400
#define OFF_GACC   2678784
#define OFF_TK     2679552

#define NBLK_U     96             // K2 [0,96): u-dot
#define NBLK_FOLD  32             // K2 [96,128): segpart fold ([96,112)=A, [112,128)=B)
#define NBLK_HEAVY 2048           // K2 [128, 2176)
#define NBLK_K2    (NBLK_U + NBLK_FOLD + NBLK_HEAVY)   // 2176 = 16 * 136

__device__ __forceinline__ unsigned short f2bf(float x) {
    unsigned u = __float_as_uint(x);
    u = (u + 0x7FFFu + ((u >> 16) & 1u)) >> 16;   // RNE
    return (unsigned short)u;
}

__device__ __forceinline__ float wave_red(float v) {
#pragma unroll
    for (int o = 32; o > 0; o >>= 1) v += __shfl_down(v, o, 64);
    return v;
}

// async 16B global -> LDS DMA (dest = wave-uniform base + lane*16)
typedef __attribute__((address_space(3))) unsigned int as3_u32;
typedef const __attribute__((address_space(1))) unsigned int as1_u32;
__device__ __forceinline__ void stage16(void* l, const void* g) {
    __builtin_amdgcn_global_load_lds((as1_u32*)g, (as3_u32*)l, 16, 0, 0);
}

// ---- K1: convert + colsums + argmax/segsum (PLAIN-STORE segparts) + zero ----
// R15 lesson: k_prep's 393K device atomics into 32KB Aseg/Bseg were ~30us of
// serialized coherence traffic. segparts plain stores run at full write BW;
// K2 reads them across the (coherent) kernel boundary.
// blocks [0,128):   convert Uc->bf16 fragment tiles (store-coalesced)
// blocks [128,192): Ur colsums (256 rows)  -> cpr[b]
// blocks [192,224): Uc colsums (256 rows)  -> cpc[b]
// blocks [224,288): Ur argmax+segsum (256 rows) -> segparts[b]      (plain)
// blocks [288,320): Uc argmax+segsum (256 rows) -> segparts[64+b]   (plain)
// block  320:       zero Aseg/Bseg/Gacc/tickets (replaces the memset node)
__global__ __launch_bounds__(256)
void k_prep(const float* __restrict__ Ur, const float* __restrict__ Uc,
            float* __restrict__ cpr, float* __restrict__ cpc,
            unsigned short* __restrict__ Ucb, float* __restrict__ segparts,
            float* __restrict__ Aseg, float* __restrict__ Bseg,
            double* __restrict__ Gacc, unsigned* __restrict__ tickets) {
    __shared__ __align__(16) unsigned char smem[17408];
    int blk = blockIdx.x, tid = threadIdx.x;
    if (blk < 128) {
        // Ucb tile t (2KB, rows 16t..16t+15), chunk o at t*2048+o*16;
        // o<64 -> q=o>>4,m=o&15 ; o>=64 -> q=4+((o-64)>>4), m=(o-64)&15.
        int gid = blk * 256 + tid;
        for (int c = gid; c < N_ATT * 8; c += 32768) {
            int t = c >> 7, o = c & 127;
            int q, m;
            if (o < 64) { q = o >> 4; m = o & 15; }
            else        { q = 4 + ((o - 64) >> 4); m = (o - 64) & 15; }
            int r = t * 16 + m;
            const float4* src = (const float4*)(Uc + (size_t)r * 64 + q * 8);
            float4 x0 = src[0], x1 = src[1];
            uint4 v;
            v.x = (unsigned)f2bf(x0.x) | ((unsigned)f2bf(x0.y) << 16);
            v.y = (unsigned)f2bf(x0.z) | ((unsigned)f2bf(x0.w) << 16);
            v.z = (unsigned)f2bf(x1.x) | ((unsigned)f2bf(x1.y) << 16);
            v.w = (unsigned)f2bf(x1.z) | ((unsigned)f2bf(x1.w) << 16);
            *(uint4*)((unsigned char*)Ucb + (size_t)c * 16) = v;
        }
        return;
    }
    if (blk == 320) {
        float4 z4 = {0.f, 0.f, 0.f, 0.f};
        for (int i = tid; i < 1024; i += 256) ((float4*)Aseg)[i] = z4;
        for (int i = tid; i < 1024; i += 256) ((float4*)Bseg)[i] = z4;
        if (tid < 96) Gacc[tid] = 0.0;
        if (tid < 64) { tickets[tid] = 0u; tickets[64 + tid] = 0u;
                        tickets[128 + tid] = 0u; tickets[192 + tid] = 0u; }
        if (tid < 16) tickets[256 + tid] = 0u;
        return;
    }
    if (blk < 224) {
        float* cs2 = (float*)smem;
        bool isUr = blk < 192;
        int b = isUr ? (blk - 128) : (blk - 192);
        const float* base = (isUr ? Ur : Uc) + (size_t)b * 256 * KDIM;
        float* dst = (isUr ? cpr : cpc) + b * 64;
        int col = tid & 63, r0 = tid >> 6;
        float s = 0.f;
        for (int r = r0; r < 256; r += 4) s += base[r * KDIM + col];
        cs2[tid] = s;
        __syncthreads();
        if (tid < 64) dst[tid] = cs2[tid] + cs2[tid + 64] + cs2[tid + 128] + cs2[tid + 192];
        return;
    }
    float* Part = (float*)smem;                      // 4096 f32
    int*   bins = (int*)(smem + 16384);              // 256 ints
    bool isUr = blk < 288;
    int b = isUr ? (blk - 224) : (blk - 288);
    const float* M = isUr ? Ur : Uc;
    int segidx = isUr ? b : (64 + b);
    int base_row = b * 256;
    int wvi = tid >> 6, lane = tid & 63;

    for (int i = tid; i < 4096; i += 256) Part[i] = 0.f;
    __syncthreads();
    {   // phase 1: row-per-thread argmax (pure VALU)
        const float* rp = M + (size_t)(base_row + tid) * KDIM;
        float best = -1e30f; int bidx = 0;
#pragma unroll
        for (int k = 0; k < 64; k += 4) {
            float4 v = *(const float4*)(rp + k);
            if (v.x > best) { best = v.x; bidx = k; }
            if (v.y > best) { best = v.y; bidx = k + 1; }
            if (v.z > best) { best = v.z; bidx = k + 2; }
            if (v.w > best) { best = v.w; bidx = k + 3; }
        }
        bins[tid] = bidx;
    }
    __syncthreads();
    {   // phase 2: one fire-and-forget ds_add per row per wave
        int r0 = wvi * 64;
        const float* Mb = M + (size_t)(base_row + r0) * 64 + lane;
#pragma unroll 4
        for (int r = 0; r < 64; ++r) {
            int bb = bins[r0 + r];
            float val = Mb[(size_t)r * 64];
            atomicAdd(&Part[bb * 64 + lane], val);
        }
    }
    __syncthreads();
    float* sp = segparts + (size_t)segidx * 4096;    // plain coalesced stores
    for (int i = tid; i < 4096; i += 256) sp[i] = Part[i];
}

// ---- K2: u-dots (96) + fold (32) + heavy (2048, async-LDS) + ticketed final ----
__global__ __launch_bounds__(256)
void k_main(const float* __restrict__ Ur, const float* __restrict__ Uc,
            const unsigned char* __restrict__ Ucb,
            const float* __restrict__ cpr, const float* __restrict__ cpc,
            const float* __restrict__ segparts,
            float* __restrict__ Aseg, float* __restrict__ Bseg,
            double* __restrict__ Gacc, unsigned* __restrict__ tickets,
            float* __restrict__ out) {
    __shared__ __align__(16) unsigned char smem[16400];
    __shared__ int flagS;
    int tid = threadIdx.x, blk = blockIdx.x;
    int wvi = tid >> 6, lane = tid & 63;

    if (blk < NBLK_U) {
        // ---------- u-dot: u=row.colsum(other), Gacc += u*log2(u) ----------
        float* wv = (float*)smem;
        bool isUr = blk < 64;
        int b = isUr ? blk : (blk - 64);
        const float* M = isUr ? Ur : Uc;
        int base_row = b * 256;
        if (tid < 64) {
            const float* cpw = isUr ? cpc : cpr;
            int nbw = isUr ? 32 : 64;
            float s = 0.f;
            for (int p = 0; p < nbw; ++p) s += cpw[p * 64 + tid];
            wv[tid] = s;
        }
        __syncthreads();
        const float* rp = M + (size_t)(base_row + tid) * KDIM;
        float u = 0.f;
#pragma unroll
        for (int k = 0; k < 64; k += 4) {
            float4 v = *(const float4*)(rp + k);
            u += v.x * wv[k] + v.y * wv[k + 1] + v.z * wv[k + 2] + v.w * wv[k + 3];
        }
        float pw = wave_red(u * __log2f(u));
        if (lane == 0)
            atomicAdd(&Gacc[(isUr ? 64 : 80) + (b & 15)], (double)pw);
    } else if (blk < NBLK_U + NBLK_FOLD) {
        // ---------- fold: segparts -> Aseg/Bseg, ONE atomic per element ----------
        bool isA = blk < (NBLK_U + 16);
        int fb = isA ? (blk - NBLK_U) : (blk - NBLK_U - 16);
        int j = fb * 256 + tid;                      // element this thread owns
        const float* sp = segparts + (isA ? 0 : (size_t)64 * 4096);
        int ns = isA ? 64 : 32;
        float s = 0.f;
        for (int p = 0; p < ns; ++p) s += sp[(size_t)p * 4096 + j];   // coalesced
        atomicAdd((isA ? Aseg : Bseg) + j, s);       // 8192 atomics total
    } else {
        // ---------- heavy: G += d*log2(d), MFMA, 2-pair double-buffered LDS ----------
        unsigned char* bufs = smem;                  // 2 x 8192 B
        float* gshW = (float*)(smem + 16384);
        int hb = blk - NBLK_U - NBLK_FOLD;
        int quad = lane >> 4, m = lane & 15;
        int rb = hb & 127, cc = hb >> 7;
        int row0 = rb * 128 + wvi * 32;
        bf16x8 a[2][2];
#pragma unroll
        for (int t = 0; t < 2; ++t) {
            int ridx = row0 + t * 16 + m;
            const float* rp = Ur + (size_t)ridx * 64 + quad * 8;
#pragma unroll
            for (int h = 0; h < 2; ++h) {
                const float* rph = rp + h * 32;
                float4 x0 = *(const float4*)rph;
                float4 x1 = *(const float4*)(rph + 4);
                bf16x8 f;
                f[0] = (short)f2bf(x0.x); f[1] = (short)f2bf(x0.y);
                f[2] = (short)f2bf(x0.z); f[3] = (short)f2bf(x0.w);
                f[4] = (short)f2bf(x1.x); f[5] = (short)f2bf(x1.y);
                f[6] = (short)f2bf(x1.z); f[7] = (short)f2bf(x1.w);
                a[t][h] = f;
            }
        }
        const unsigned char* gB = Ucb + (size_t)(cc * 32) * 2048;
        int soff = wvi * 2048 + lane * 16;
        stage16(bufs + soff, gB + soff);
        stage16(bufs + soff + 1024, gB + soff + 1024);
        int loff = lane * 16;
        float g = 0.f;
#pragma unroll 1
        for (int pg = 0; pg < 8; ++pg) {
            __syncthreads();
            if (pg < 7) {
                const unsigned char* gn = gB + (size_t)(pg + 1) * 8192;
                unsigned char* bn = bufs + (((pg + 1) & 1) << 13);
                stage16(bn + soff, gn + soff);
                stage16(bn + soff + 1024, gn + soff + 1024);
            }
            const unsigned char* bg = bufs + ((pg & 1) << 13);
#pragma unroll
            for (int p = 0; p < 2; ++p) {
                const unsigned char* bb = bg + p * 4096;
                bf16x8 c00 = *(const bf16x8*)(bb + loff);
                bf16x8 c01 = *(const bf16x8*)(bb + 1024 + loff);
                bf16x8 c10 = *(const bf16x8*)(bb + 2048 + loff);
                bf16x8 c11 = *(const bf16x8*)(bb + 3072 + loff);
                f32x4 acc00 = {0.f,0.f,0.f,0.f}, acc01 = {0.f,0.f,0.f,0.f};
                f32x4 acc10 = {0.f,0.f,0.f,0.f}, acc11 = {0.f,0.f,0.f,0.f};
                acc00 = __builtin_amdgcn_mfma_f32_16x16x32_bf16(a[0][0], c00, acc00, 0, 0, 0);
                acc00 = __builtin_amdgcn_mfma_f32_16x16x32_bf16(a[0][1], c01, acc00, 0, 0, 0);
                acc10 = __builtin_amdgcn_mfma_f32_16x16x32_bf16(a[1][0], c00, acc10, 0, 0, 0);
                acc10 = __builtin_amdgcn_mfma_f32_16x16x32_bf16(a[1][1], c01, acc10, 0, 0, 0);
                acc01 = __builtin_amdgcn_mfma_f32_16x16x32_bf16(a[0][0], c10, acc01, 0, 0, 0);
                acc01 = __builtin_amdgcn_mfma_f32_16x16x32_bf16(a[0][1], c11, acc01, 0, 0, 0);
                acc11 = __builtin_amdgcn_mfma_f32_16x16x32_bf16(a[1][0], c10, acc11, 0, 0, 0);
                acc11 = __builtin_amdgcn_mfma_f32_16x16x32_bf16(a[1][1], c11, acc11, 0, 0, 0);
                // tile-sum is permutation-invariant -> C/D layout irrelevant;
                // dropping +eps*S (~2e-6 vs d~16) perturbs mi_org ~2e-7 << thresh
#pragma unroll
                for (int e = 0; e < 4; ++e) {
                    float d0 = acc00[e]; g += d0 * __log2f(d0);
                    float d1 = acc01[e]; g += d1 * __log2f(d1);
                    float d2 = acc10[e]; g += d2 * __log2f(d2);
                    float d3 = acc11[e]; g += d3 * __log2f(d3);
                }
            }
        }
        float gw = wave_red(g);
        if (lane == 0) gshW[wvi] = gw;
        __syncthreads();
        if (tid == 0) {
            float gs = gshW[0] + gshW[1] + gshW[2] + gshW[3];
            atomicAdd(&Gacc[hb & 63], (double)gs);
        }
    }

    // ---------- common tail: drain own atomics, line-padded sharded ticket ----------
    __builtin_amdgcn_s_waitcnt(0);
    __syncthreads();
    if (tid == 0) {
        flagS = 0;
        unsigned old = atomicAdd(&tickets[(blk & 15) << 4], 1u);  // own 64B line
        if (old == (NBLK_K2 / 16) - 1) {
            unsigned old2 = atomicAdd(&tickets[256], 1u);
            flagS = (old2 == 15u);
        }
    }
    __syncthreads();
    if (!flagS) return;

    // final: Aseg/Bseg/Gacc atomic-written (coherent); cpr/cpc boundary-coherent.
    float*  Prx = (float*)smem;
    float*  Pry = (float*)(smem + 256);
    double* sc  = (double*)(smem + 512);             // S,G,Uu,Vv
    double* red = (double*)(smem + 1024);            // 256 f64
    if (tid < 64) {
        double sa = 0.0, sb = 0.0;
        for (int p = 0; p < 64; ++p) sa += (double)cpr[p * 64 + tid];
        for (int p = 0; p < 32; ++p) sb += (double)cpc[p * 64 + tid];
        red[tid] = sa * sb;
        Prx[tid] = 0.f; Pry[tid] = 0.f;
    }
    __syncthreads();
    if (tid == 0) {
        double s = 0.0;
        for (int k = 0; k < 64; ++k) s += red[k];
        sc[0] = s;
        double gg = 0.0;
        for (int k = 0; k < 64; ++k) gg += Gacc[k];
        sc[1] = gg;
    } else if (tid == 1) {
        double s = 0.0;
        for (int k = 64; k < 80; ++k) s += Gacc[k];
        sc[2] = s;
    } else if (tid == 2) {
        double s = 0.0;
        for (int k = 80; k < 96; ++k) s += Gacc[k];
        sc[3] = s;
    }
    __syncthreads();
    double S = sc[0];
    int p = tid >> 2, q0 = (tid & 3) * 16;
    float tloc[16];
    {
        float prow_sum = 0.f;
        for (int qi = 0; qi < 16; ++qi) {
            int q = q0 + qi;
            double s = 0.0;
            for (int k = 0; k < 64; ++k)
                s += (double)Aseg[p * 64 + k] * (double)Bseg[q * 64 + k];
            float t = (float)(s / S);
            tloc[qi] = t;
            prow_sum += t;
            atomicAdd(&Pry[q], t);
        }
        atomicAdd(&Prx[p], prow_sum);
    }
    __syncthreads();
    {
        const double EPSd = 1e-15;
        double part = 0.0;
        for (int qi = 0; qi < 16; ++qi) {
            double t = (double)tloc[qi];
            double txy = (double)Prx[p] * (double)Pry[q0 + qi];
            part += t * log((t + EPSd) / (txy + EPSd));
        }
        red[tid] = part;
    }
    __syncthreads();
    for (int s2 = 128; s2 > 0; s2 >>= 1) {
        if (tid < s2) red[tid] += red[tid + s2];
        __syncthreads();
    }
    if (tid == 0) {
        const double inv_ln2 = 1.4426950408889634;
        double mi_red = red[0] * inv_ln2;
        double G = sc[1], Uu = sc[2], Vv = sc[3];
        double log2S = log(S) * inv_ln2;
        double mi_org = G / S + log2S - (Uu + Vv) / S;
        double loss = log(1.0 + fabs(1.0 - mi_red / mi_org));
        out[0] = (float)loss;
    }
}

extern "C" void kernel_launch(void* const* d_in, const int* in_sizes, int n_in,
                              void* d_out, int out_size, void* d_ws, size_t ws_size,
                              hipStream_t stream) {
    const float* Ur = (const float*)d_in[0];
    const float* Uc = (const float*)d_in[1];
    float* out = (float*)d_out;
    char* ws = (char*)d_ws;
    unsigned short* Ucb = (unsigned short*)(ws + OFF_UCB);
    float* cpr   = (float*)(ws + OFF_CPR);
    float* cpc   = (float*)(ws + OFF_CPC);
    float* segparts = (float*)(ws + OFF_SEGP);
    float* Aseg  = (float*)(ws + OFF_ASEG);
    float* Bseg  = (float*)(ws + OFF_BSEG);
    double* Gacc = (double*)(ws + OFF_GACC);
    unsigned* tickets = (unsigned*)(ws + OFF_TK);

    k_prep<<<321, 256, 0, stream>>>(Ur, Uc, cpr, cpc, Ucb, segparts,
                                    Aseg, Bseg, Gacc, tickets);
    k_main<<<NBLK_K2, 256, 0, stream>>>(Ur, Uc, (const unsigned char*)Ucb,
                                        cpr, cpc, segparts, Aseg, Bseg,
                                        Gacc, tickets, out);
}

// Round 19
// 161.690 us; speedup vs baseline: 1.2544x; 1.0233x over previous
//
#include <hip/hip_runtime.h>
#include <hip/hip_bf16.h>

#define N_INS 16384
#define N_ATT 8192
#define KDIM  64

typedef __attribute__((ext_vector_type(8))) short bf16x8;
typedef __attribute__((ext_vector_type(4))) float f32x4;

// ws layout (bytes):
// 0:       bf16 Ucb[8192*64] (1 MiB, fragment-order tiles)  [K1 writes all]
// 1048576: float cpr[64][64]                                 [K1 writes all]
// 1064960: float cpc[32][64]                                 [K1 writes all]
// 1073152: float Aseg[4096]  (zeroed by K1; atomic-accumulated in K2)
// 1089536: float Bseg[4096]  (zeroed by K1; atomic-accumulated in K2)
// 1105920: double Gacc[96]   ([0,64)=G, [64,80)=Uu, [80,96)=Vv; K1 zeroes)
// 1106688: unsigned tickets[272] (shard s at [s*16], global at [256]; K1 zeroes)
#define OFF_UCB    0
#define OFF_CPR    1048576
#define OFF_CPC    1064960
#define OFF_ASEG   1073152
#define OFF_BSEG   1089536
#define OFF_GACC   1105920
#define OFF_TK     1106688

#define NBLK_SEG   96             // K2 [0,96): argmax+segsum (256 rows each)
#define NBLK_U     96             // K2 [96,192): u-dot
#define NBLK_HEAVY 2048           // K2 [192, 2240)
#define NBLK_K2    (NBLK_SEG + NBLK_U + NBLK_HEAVY)   // 2240 = 16 * 140

__device__ __forceinline__ unsigned short f2bf(float x) {
    unsigned u = __float_as_uint(x);
    u = (u + 0x7FFFu + ((u >> 16) & 1u)) >> 16;   // RNE
    return (unsigned short)u;
}

__device__ __forceinline__ float wave_red(float v) {
#pragma unroll
    for (int o = 32; o > 0; o >>= 1) v += __shfl_down(v, o, 64);
    return v;
}

// async 16B global -> LDS DMA (dest = wave-uniform base + lane*16)
typedef __attribute__((address_space(3))) unsigned int as3_u32;
typedef const __attribute__((address_space(1))) unsigned int as1_u32;
__device__ __forceinline__ void stage16(void* l, const void* g) {
    __builtin_amdgcn_global_load_lds((as1_u32*)g, (as3_u32*)l, 16, 0, 0);
}

// ---- K1: convert + colsums + zero. The argmax/segsum phase (57us, latency-
// bound, depends ONLY on raw Ur/Uc) moved to K2 to hide under heavy's wall.
// R18 lesson: cooperative launch fails in this harness (output never written
// on the first non-captured call) — overlap achieved with block-role split
// inside a normal launch instead.
// blocks [0,128):   convert Uc->bf16 fragment tiles (store-coalesced)
// blocks [128,192): Ur colsums (256 rows)  -> cpr[b]
// blocks [192,224): Uc colsums (256 rows)  -> cpc[b]
// block  224:       zero Aseg/Bseg/Gacc/tickets
__global__ __launch_bounds__(256)
void k_prep(const float* __restrict__ Ur, const float* __restrict__ Uc,
            float* __restrict__ cpr, float* __restrict__ cpc,
            unsigned short* __restrict__ Ucb,
            float* __restrict__ Aseg, float* __restrict__ Bseg,
            double* __restrict__ Gacc, unsigned* __restrict__ tickets) {
    __shared__ float cs2[256];
    int blk = blockIdx.x, tid = threadIdx.x;
    if (blk < 128) {
        // Ucb tile t (2KB, rows 16t..16t+15), chunk o at t*2048+o*16;
        // o<64 -> q=o>>4,m=o&15 ; o>=64 -> q=4+((o-64)>>4), m=(o-64)&15.
        int gid = blk * 256 + tid;
        for (int c = gid; c < N_ATT * 8; c += 32768) {
            int t = c >> 7, o = c & 127;
            int q, m;
            if (o < 64) { q = o >> 4; m = o & 15; }
            else        { q = 4 + ((o - 64) >> 4); m = (o - 64) & 15; }
            int r = t * 16 + m;
            const float4* src = (const float4*)(Uc + (size_t)r * 64 + q * 8);
            float4 x0 = src[0], x1 = src[1];
            uint4 v;
            v.x = (unsigned)f2bf(x0.x) | ((unsigned)f2bf(x0.y) << 16);
            v.y = (unsigned)f2bf(x0.z) | ((unsigned)f2bf(x0.w) << 16);
            v.z = (unsigned)f2bf(x1.x) | ((unsigned)f2bf(x1.y) << 16);
            v.w = (unsigned)f2bf(x1.z) | ((unsigned)f2bf(x1.w) << 16);
            *(uint4*)((unsigned char*)Ucb + (size_t)c * 16) = v;
        }
        return;
    }
    if (blk == 224) {
        float4 z4 = {0.f, 0.f, 0.f, 0.f};
        for (int i = tid; i < 1024; i += 256) ((float4*)Aseg)[i] = z4;
        for (int i = tid; i < 1024; i += 256) ((float4*)Bseg)[i] = z4;
        if (tid < 96) Gacc[tid] = 0.0;
        if (tid < 64) { tickets[tid] = 0u; tickets[64 + tid] = 0u;
                        tickets[128 + tid] = 0u; tickets[192 + tid] = 0u; }
        if (tid < 16) tickets[256 + tid] = 0u;
        return;
    }
    bool isUr = blk < 192;
    int b = isUr ? (blk - 128) : (blk - 192);
    const float* base = (isUr ? Ur : Uc) + (size_t)b * 256 * KDIM;
    float* dst = (isUr ? cpr : cpc) + b * 64;
    int col = tid & 63, r0 = tid >> 6;
    float s = 0.f;
    for (int r = r0; r < 256; r += 4) s += base[r * KDIM + col];
    cs2[tid] = s;
    __syncthreads();
    if (tid < 64) dst[tid] = cs2[tid] + cs2[tid + 64] + cs2[tid + 128] + cs2[tid + 192];
}

// ---- K2: argmax/segsum (96, overlapped) + u-dots (96) + heavy (2048) + final ----
// Segment sums LDS-accumulate then atomicAdd into Aseg/Bseg (393K atomics,
// ~25us serialized at coherence point — hidden under heavy's ~85us wall; the
// same storm in serial K1 cost 30us on the critical path, R15). Atomic writes
// are memory-side coherent so the ticketed final's plain reads are safe (R17).
__global__ __launch_bounds__(256)
void k_main(const float* __restrict__ Ur, const float* __restrict__ Uc,
            const unsigned char* __restrict__ Ucb,
            const float* __restrict__ cpr, const float* __restrict__ cpc,
            float* __restrict__ Aseg, float* __restrict__ Bseg,
            double* __restrict__ Gacc, unsigned* __restrict__ tickets,
            float* __restrict__ out) {
    __shared__ __align__(16) unsigned char smem[17408];
    __shared__ int flagS;
    int tid = threadIdx.x, blk = blockIdx.x;
    int wvi = tid >> 6, lane = tid & 63;

    if (blk < NBLK_SEG) {
        // ---------- argmax + segment-sum, 256 rows (R17 k_prep structure) ----------
        float* Part = (float*)smem;                  // 4096 f32
        int*   bins = (int*)(smem + 16384);          // 256 ints
        bool isUr = blk < 64;
        int b = isUr ? blk : (blk - 64);
        const float* M = isUr ? Ur : Uc;
        float* Seg = isUr ? Aseg : Bseg;
        int base_row = b * 256;
        for (int i = tid; i < 4096; i += 256) Part[i] = 0.f;
        __syncthreads();
        {   // phase 1: row-per-thread argmax (pure VALU)
            const float* rp = M + (size_t)(base_row + tid) * KDIM;
            float best = -1e30f; int bidx = 0;
#pragma unroll
            for (int k = 0; k < 64; k += 4) {
                float4 v = *(const float4*)(rp + k);
                if (v.x > best) { best = v.x; bidx = k; }
                if (v.y > best) { best = v.y; bidx = k + 1; }
                if (v.z > best) { best = v.z; bidx = k + 2; }
                if (v.w > best) { best = v.w; bidx = k + 3; }
            }
            bins[tid] = bidx;
        }
        __syncthreads();
        {   // phase 2: one fire-and-forget ds_add per row per wave
            int r0 = wvi * 64;
            const float* Mb = M + (size_t)(base_row + r0) * 64 + lane;
#pragma unroll 4
            for (int r = 0; r < 64; ++r) {
                int bb = bins[r0 + r];
                float val = Mb[(size_t)r * 64];
                atomicAdd(&Part[bb * 64 + lane], val);
            }
        }
        __syncthreads();
        for (int i = tid; i < 4096; i += 256)        // coalesced global fold
            atomicAdd(&Seg[i], Part[i]);
    } else if (blk < NBLK_SEG + NBLK_U) {
        // ---------- u-dot: u=row.colsum(other), Gacc += u*log2(u) ----------
        float* wv = (float*)smem;
        bool isUr = blk < (NBLK_SEG + 64);
        int b = isUr ? (blk - NBLK_SEG) : (blk - NBLK_SEG - 64);
        const float* M = isUr ? Ur : Uc;
        int base_row = b * 256;
        if (tid < 64) {
            const float* cpw = isUr ? cpc : cpr;
            int nbw = isUr ? 32 : 64;
            float s = 0.f;
            for (int p = 0; p < nbw; ++p) s += cpw[p * 64 + tid];
            wv[tid] = s;
        }
        __syncthreads();
        const float* rp = M + (size_t)(base_row + tid) * KDIM;
        float u = 0.f;
#pragma unroll
        for (int k = 0; k < 64; k += 4) {
            float4 v = *(const float4*)(rp + k);
            u += v.x * wv[k] + v.y * wv[k + 1] + v.z * wv[k + 2] + v.w * wv[k + 3];
        }
        float pw = wave_red(u * __log2f(u));
        if (lane == 0)
            atomicAdd(&Gacc[(isUr ? 64 : 80) + (b & 15)], (double)pw);
    } else {
        // ---------- heavy: G += d*log2(d), MFMA, 2-pair dbuf LDS (R17) ----------
        unsigned char* bufs = smem;                  // 2 x 8192 B
        float* gshW = (float*)(smem + 16384);
        int hb = blk - NBLK_SEG - NBLK_U;
        int quad = lane >> 4, m = lane & 15;
        int rb = hb & 127, cc = hb >> 7;
        int row0 = rb * 128 + wvi * 32;
        bf16x8 a[2][2];
#pragma unroll
        for (int t = 0; t < 2; ++t) {
            int ridx = row0 + t * 16 + m;
            const float* rp = Ur + (size_t)ridx * 64 + quad * 8;
#pragma unroll
            for (int h = 0; h < 2; ++h) {
                const float* rph = rp + h * 32;
                float4 x0 = *(const float4*)rph;
                float4 x1 = *(const float4*)(rph + 4);
                bf16x8 f;
                f[0] = (short)f2bf(x0.x); f[1] = (short)f2bf(x0.y);
                f[2] = (short)f2bf(x0.z); f[3] = (short)f2bf(x0.w);
                f[4] = (short)f2bf(x1.x); f[5] = (short)f2bf(x1.y);
                f[6] = (short)f2bf(x1.z); f[7] = (short)f2bf(x1.w);
                a[t][h] = f;
            }
        }
        const unsigned char* gB = Ucb + (size_t)(cc * 32) * 2048;
        int soff = wvi * 2048 + lane * 16;
        stage16(bufs + soff, gB + soff);
        stage16(bufs + soff + 1024, gB + soff + 1024);
        int loff = lane * 16;
        float g = 0.f;
#pragma unroll 1
        for (int pg = 0; pg < 8; ++pg) {
            __syncthreads();
            if (pg < 7) {
                const unsigned char* gn = gB + (size_t)(pg + 1) * 8192;
                unsigned char* bn = bufs + (((pg + 1) & 1) << 13);
                stage16(bn + soff, gn + soff);
                stage16(bn + soff + 1024, gn + soff + 1024);
            }
            const unsigned char* bg = bufs + ((pg & 1) << 13);
#pragma unroll
            for (int p = 0; p < 2; ++p) {
                const unsigned char* bb = bg + p * 4096;
                bf16x8 c00 = *(const bf16x8*)(bb + loff);
                bf16x8 c01 = *(const bf16x8*)(bb + 1024 + loff);
                bf16x8 c10 = *(const bf16x8*)(bb + 2048 + loff);
                bf16x8 c11 = *(const bf16x8*)(bb + 3072 + loff);
                f32x4 acc00 = {0.f,0.f,0.f,0.f}, acc01 = {0.f,0.f,0.f,0.f};
                f32x4 acc10 = {0.f,0.f,0.f,0.f}, acc11 = {0.f,0.f,0.f,0.f};
                acc00 = __builtin_amdgcn_mfma_f32_16x16x32_bf16(a[0][0], c00, acc00, 0, 0, 0);
                acc00 = __builtin_amdgcn_mfma_f32_16x16x32_bf16(a[0][1], c01, acc00, 0, 0, 0);
                acc10 = __builtin_amdgcn_mfma_f32_16x16x32_bf16(a[1][0], c00, acc10, 0, 0, 0);
                acc10 = __builtin_amdgcn_mfma_f32_16x16x32_bf16(a[1][1], c01, acc10, 0, 0, 0);
                acc01 = __builtin_amdgcn_mfma_f32_16x16x32_bf16(a[0][0], c10, acc01, 0, 0, 0);
                acc01 = __builtin_amdgcn_mfma_f32_16x16x32_bf16(a[0][1], c11, acc01, 0, 0, 0);
                acc11 = __builtin_amdgcn_mfma_f32_16x16x32_bf16(a[1][0], c10, acc11, 0, 0, 0);
                acc11 = __builtin_amdgcn_mfma_f32_16x16x32_bf16(a[1][1], c11, acc11, 0, 0, 0);
                // tile-sum permutation-invariant -> C/D layout irrelevant;
                // +eps*S dropped (~2e-6 vs d~16): mi_org shift ~2e-7 << thresh
#pragma unroll
                for (int e = 0; e < 4; ++e) {
                    float d0 = acc00[e]; g += d0 * __log2f(d0);
                    float d1 = acc01[e]; g += d1 * __log2f(d1);
                    float d2 = acc10[e]; g += d2 * __log2f(d2);
                    float d3 = acc11[e]; g += d3 * __log2f(d3);
                }
            }
        }
        float gw = wave_red(g);
        if (lane == 0) gshW[wvi] = gw;
        __syncthreads();
        if (tid == 0) {
            float gs = gshW[0] + gshW[1] + gshW[2] + gshW[3];
            atomicAdd(&Gacc[hb & 63], (double)gs);
        }
    }

    // ---------- common tail: drain own atomics, line-padded sharded ticket ----------
    __builtin_amdgcn_s_waitcnt(0);                   // all this block's atomics acked
    __syncthreads();
    if (tid == 0) {
        flagS = 0;
        unsigned old = atomicAdd(&tickets[(blk & 15) << 4], 1u);  // own 64B line
        if (old == (NBLK_K2 / 16) - 1) {
            unsigned old2 = atomicAdd(&tickets[256], 1u);
            flagS = (old2 == 15u);
        }
    }
    __syncthreads();
    if (!flagS) return;

    // final: Aseg/Bseg/Gacc atomic-written (coherent); cpr/cpc boundary-coherent.
    float*  Prx = (float*)smem;
    float*  Pry = (float*)(smem + 256);
    double* sc  = (double*)(smem + 512);             // S,G,Uu,Vv
    double* red = (double*)(smem + 1024);            // 256 f64
    if (tid < 64) {
        double sa = 0.0, sb = 0.0;
        for (int p = 0; p < 64; ++p) sa += (double)cpr[p * 64 + tid];
        for (int p = 0; p < 32; ++p) sb += (double)cpc[p * 64 + tid];
        red[tid] = sa * sb;
        Prx[tid] = 0.f; Pry[tid] = 0.f;
    }
    __syncthreads();
    if (tid == 0) {
        double s = 0.0;
        for (int k = 0; k < 64; ++k) s += red[k];
        sc[0] = s;
        double gg = 0.0;
        for (int k = 0; k < 64; ++k) gg += Gacc[k];
        sc[1] = gg;
    } else if (tid == 1) {
        double s = 0.0;
        for (int k = 64; k < 80; ++k) s += Gacc[k];
        sc[2] = s;
    } else if (tid == 2) {
        double s = 0.0;
        for (int k = 80; k < 96; ++k) s += Gacc[k];
        sc[3] = s;
    }
    __syncthreads();
    double S = sc[0];
    int p = tid >> 2, q0 = (tid & 3) * 16;
    float tloc[16];
    {
        float prow_sum = 0.f;
        for (int qi = 0; qi < 16; ++qi) {
            int q = q0 + qi;
            double s = 0.0;
            for (int k = 0; k < 64; ++k)
                s += (double)Aseg[p * 64 + k] * (double)Bseg[q * 64 + k];
            float t = (float)(s / S);
            tloc[qi] = t;
            prow_sum += t;
            atomicAdd(&Pry[q], t);
        }
        atomicAdd(&Prx[p], prow_sum);
    }
    __syncthreads();
    {
        const double EPSd = 1e-15;
        double part = 0.0;
        for (int qi = 0; qi < 16; ++qi) {
            double t = (double)tloc[qi];
            double txy = (double)Prx[p] * (double)Pry[q0 + qi];
            part += t * log((t + EPSd) / (txy + EPSd));
        }
        red[tid] = part;
    }
    __syncthreads();
    for (int s2 = 128; s2 > 0; s2 >>= 1) {
        if (tid < s2) red[tid] += red[tid + s2];
        __syncthreads();
    }
    if (tid == 0) {
        const double inv_ln2 = 1.4426950408889634;
        double mi_red = red[0] * inv_ln2;
        double G = sc[1], Uu = sc[2], Vv = sc[3];
        double log2S = log(S) * inv_ln2;
        double mi_org = G / S + log2S - (Uu + Vv) / S;
        double loss = log(1.0 + fabs(1.0 - mi_red / mi_org));
        out[0] = (float)loss;
    }
}

extern "C" void kernel_launch(void* const* d_in, const int* in_sizes, int n_in,
                              void* d_out, int out_size, void* d_ws, size_t ws_size,
                              hipStream_t stream) {
    const float* Ur = (const float*)d_in[0];
    const float* Uc = (const float*)d_in[1];
    float* out = (float*)d_out;
    char* ws = (char*)d_ws;
    unsigned short* Ucb = (unsigned short*)(ws + OFF_UCB);
    float* cpr   = (float*)(ws + OFF_CPR);
    float* cpc   = (float*)(ws + OFF_CPC);
    float* Aseg  = (float*)(ws + OFF_ASEG);
    float* Bseg  = (float*)(ws + OFF_BSEG);
    double* Gacc = (double*)(ws + OFF_GACC);
    unsigned* tickets = (unsigned*)(ws + OFF_TK);

    k_prep<<<225, 256, 0, stream>>>(Ur, Uc, cpr, cpc, Ucb, Aseg, Bseg, Gacc, tickets);
    k_main<<<NBLK_K2, 256, 0, stream>>>(Ur, Uc, (const unsigned char*)Ucb,
                                        cpr, cpc, Aseg, Bseg, Gacc, tickets, out);
}